// Round 8
// baseline (353.255 us; speedup 1.0000x reference)
//
#include <hip/hip_runtime.h>
#include <math.h>

#define HH 480
#define WW 640
#define HW (HH*WW)

// ---------------- K1: horizontal resample + p maps (+ acc zero) ----------------

__device__ __forceinline__ float sample1(const float* __restrict__ row, float x) {
    float x0 = floorf(x);
    float w1 = x - x0;
    int xi = (int)x0;
    float v0 = (xi >= 0 && xi < WW) ? row[xi] : 0.f;
    float v1 = (xi + 1 >= 0 && xi + 1 < WW) ? row[xi + 1] : 0.f;
    return v0 * (1.f - w1) + v1 * w1;
}

__global__ __launch_bounds__(256) void k_resample(
    const float* __restrict__ left, const float* __restrict__ right,
    const float* __restrict__ dispL, const float* __restrict__ dispR,
    float* __restrict__ rir, float* __restrict__ ril,
    float* __restrict__ pL, float* __restrict__ pR,
    float* __restrict__ acc)
{
    if (blockIdx.x == 0 && threadIdx.x < 8) acc[threadIdx.x] = 0.f;
    int idx = blockIdx.x * blockDim.x + threadIdx.x;
    if (idx >= HW) return;
    int h = idx / WW;
    int w = idx - h * WW;
    float dL = dispL[idx];
    float dR = dispR[idx];
    float xl = (float)w - dL;   // sample right view at j - dispL
    float xr = (float)w + dR;   // sample left view  at j + dispR
    #pragma unroll
    for (int c = 0; c < 3; ++c) {
        rir[c*HW + idx] = sample1(right + c*HW + h*WW, xl);
        ril[c*HW + idx] = sample1(left  + c*HW + h*WW, xr);
    }
    float rdr = sample1(dispR + h*WW, xl);
    float rdl = sample1(dispL + h*WW, xr);
    pL[idx] = __expf(-0.6931f * fabsf(dL - rdr));
    pR[idx] = __expf(-0.6931f * fabsf(dR - rdl));
}

// ---------------- K2: 9x9 LCN (separable) + cost, one side per blockIdx.z ----------------
// block 32x8, tile rows 16 (8+2*4), cols 40 (32+2*4)

__global__ __launch_bounds__(256) void k_lcncost(
    const float* __restrict__ left, const float* __restrict__ right,
    const float* __restrict__ rir, const float* __restrict__ ril,
    float* __restrict__ costL, float* __restrict__ costR)
{
    __shared__ float raw[6][16][40];   // 15360 B
    __shared__ float hs [6][16][32];   // 12288 B
    __shared__ float hs2[6][16][32];   // 12288 B
    int tx = threadIdx.x, ty = threadIdx.y;
    int tid = ty * 32 + tx;
    int gx0 = blockIdx.x * 32, gy0 = blockIdx.y * 8;
    const float* __restrict__ imgA = blockIdx.z ? right : left;   // real image (std source)
    const float* __restrict__ imgB = blockIdx.z ? ril   : rir;    // reconstruction
    float* __restrict__ out = blockIdx.z ? costR : costL;

    for (int e = tid; e < 6*16*40; e += 256) {
        int a   = e / (16*40);
        int rem = e - a * (16*40);
        int r   = rem / 40;
        int x   = rem - r * 40;
        int gy = gy0 + r - 4, gx = gx0 + x - 4;
        float v = 0.f;
        if ((unsigned)gy < (unsigned)HH && (unsigned)gx < (unsigned)WW) {
            const float* s = (a < 3) ? imgA : imgB;
            int ch = (a < 3) ? a : a - 3;
            v = s[ch*HW + gy*WW + gx];
        }
        ((float*)raw)[e] = v;
    }
    __syncthreads();

    for (int e = tid; e < 6*16*32; e += 256) {
        int a   = e / (16*32);
        int rem = e - a * (16*32);
        int r   = rem / 32;
        int x   = rem - r * 32;
        float s = 0.f, s2 = 0.f;
        #pragma unroll
        for (int dx = 0; dx < 9; ++dx) {
            float v = raw[a][r][x + dx];
            s += v;
            s2 = fmaf(v, v, s2);
        }
        ((float*)hs)[e]  = s;
        ((float*)hs2)[e] = s2;
    }
    __syncthreads();

    int idx = (gy0 + ty) * WW + gx0 + tx;
    #pragma unroll
    for (int c = 0; c < 3; ++c) {
        float SA = 0.f, SA2 = 0.f, SB = 0.f, SB2 = 0.f;
        #pragma unroll
        for (int dy = 0; dy < 9; ++dy) {
            SA  += hs [c][ty + dy][tx];
            SA2 += hs2[c][ty + dy][tx];
            SB  += hs [3 + c][ty + dy][tx];
            SB2 += hs2[3 + c][ty + dy][tx];
        }
        float meanA = SA * (1.f/81.f);
        float stdA  = sqrtf(fmaxf(SA2 * (1.f/81.f) - meanA * meanA, 0.f)) * (81.f/80.f);
        float lcnA  = (raw[c][ty + 4][tx + 4] - meanA) / (stdA + 1e-5f);
        float meanB = SB * (1.f/81.f);
        float stdB  = sqrtf(fmaxf(SB2 * (1.f/81.f) - meanB * meanB, 0.f)) * (81.f/80.f);
        float lcnB  = (raw[3 + c][ty + 4][tx + 4] - meanB) / (stdB + 1e-5f);
        out[c*HW + idx] = fabsf((lcnA - lcnB) * stdA);
    }
}

// ---------------- K3: 12x12 ASW + losses + reduction (exp-free, row-pipelined) ----------------
// block (32,2,3) = 192 threads = 3 waves; thread (tx,ty,c): channel c of 4 outputs
// (gx0+tx, gy0+4ty+i), i=0..3; region 32x8/block; grid 20x60 = 1200 blocks.
// Tile uint2: .x = bf16(Ep)|bf16(Em)<<16, Ep=exp(g/2), Em=exp(-g/2);
//             .y = bf16(costL)|bf16(costR)<<16.
// OOB halo: g=0 => Ep=Em=1.0 (NOT zero), costs 0 — matches zero-pad reference.
// Per tap: t = exp(-|g_c-g_q|/2) = min(Em_c*Ep_q, Ep_c*Em_q) — no per-tap exp.
// Rows kap 0..14; eligibility of output i at row kap: max(0,kap-11) <= i <= min(3,kap).
// Two 12-reg buffers alternate: loadrow(next) issued before comprow(cur) so each
// row's ds_reads are in flight under the previous row's VALU work.

#define T3H 19
#define T3W 43

__device__ __forceinline__ unsigned bf16rne(float f) {
    unsigned u = __float_as_uint(f);
    return (u + 0x7fffu + ((u >> 16) & 1u)) >> 16;
}

__global__ __launch_bounds__(192) void k_asw_reduce(
    const float* __restrict__ left, const float* __restrict__ right,
    const float* __restrict__ rir, const float* __restrict__ ril,
    const float* __restrict__ costL, const float* __restrict__ costR,
    const float* __restrict__ pL, const float* __restrict__ pR,
    float* __restrict__ acc)
{
    __shared__ uint2 tile[3][T3H][T3W];   // 19608 B
    __shared__ float red[3][6];
    int tx = threadIdx.x, ty = threadIdx.y, c = threadIdx.z;
    int tid = tx + 32 * ty + 64 * c;
    int gx0 = blockIdx.x * 32, gy0 = blockIdx.y * 8;

    for (int e = tid; e < 3 * T3H * T3W; e += 192) {
        int cc  = e / (T3H * T3W);
        int rem = e - cc * (T3H * T3W);
        int r   = rem / T3W;
        int x   = rem - r * T3W;
        int gy = gy0 + r - 6, gx = gx0 + x - 6;
        uint2 v = make_uint2(0x3f803f80u, 0u);   // g=0: Ep=Em=1.0, costs 0
        if ((unsigned)gy < (unsigned)HH && (unsigned)gx < (unsigned)WW) {
            int o = cc*HW + gy*WW + gx;
            float g = left[o];
            float ep = __expf(0.5f * g);
            float em = __expf(-0.5f * g);
            v.x = bf16rne(ep) | (bf16rne(em) << 16);
            v.y = bf16rne(costL[o]) | (bf16rne(costR[o]) << 16);
        }
        tile[cc][r][x] = v;
    }
    __syncthreads();

    int ty4 = 4 * ty;
    float epc[4], emc[4];
    #pragma unroll
    for (int i = 0; i < 4; ++i) {
        unsigned vc = tile[c][ty4 + i + 6][tx + 6].x;
        epc[i] = __uint_as_float(vc << 16);
        emc[i] = __uint_as_float(vc & 0xffff0000u);
    }

    float wg[4] = {0.f,0.f,0.f,0.f}, aL[4] = {0.f,0.f,0.f,0.f}, aR[4] = {0.f,0.f,0.f,0.f};

    auto loadrow = [&](uint2* d, int kap) {
        const uint2* src = &tile[c][ty4 + kap][tx];
        #pragma unroll
        for (int dx = 0; dx < 12; ++dx) d[dx] = src[dx];
    };
    auto comprow = [&](const uint2* d, int i0, int i1) {
        #pragma unroll
        for (int dx = 0; dx < 12; ++dx) {
            uint2 v = d[dx];
            float ep = __uint_as_float(v.x << 16);
            float em = __uint_as_float(v.x & 0xffff0000u);
            float cl = __uint_as_float(v.y << 16);
            float cr = __uint_as_float(v.y & 0xffff0000u);
            #pragma unroll
            for (int i = 0; i < 4; ++i) {
                if (i >= i0 && i <= i1) {
                    float t = fminf(emc[i] * ep, epc[i] * em);
                    wg[i] += t;
                    aL[i] = fmaf(t, cl, aL[i]);
                    aR[i] = fmaf(t, cr, aR[i]);
                }
            }
        }
    };

    uint2 bufA[12], bufB[12];
    loadrow(bufA, 0);
    loadrow(bufB, 1);  comprow(bufA, 0, 0);   // row 0
    loadrow(bufA, 2);  comprow(bufB, 0, 1);   // row 1
    loadrow(bufB, 3);  comprow(bufA, 0, 2);   // row 2
    loadrow(bufA, 4);  comprow(bufB, 0, 3);   // row 3
    loadrow(bufB, 5);  comprow(bufA, 0, 3);   // row 4
    loadrow(bufA, 6);  comprow(bufB, 0, 3);   // row 5
    loadrow(bufB, 7);  comprow(bufA, 0, 3);   // row 6
    loadrow(bufA, 8);  comprow(bufB, 0, 3);   // row 7
    loadrow(bufB, 9);  comprow(bufA, 0, 3);   // row 8
    loadrow(bufA, 10); comprow(bufB, 0, 3);   // row 9
    loadrow(bufB, 11); comprow(bufA, 0, 3);   // row 10
    loadrow(bufA, 12); comprow(bufB, 0, 3);   // row 11
    loadrow(bufB, 13); comprow(bufA, 1, 3);   // row 12
    loadrow(bufA, 14); comprow(bufB, 2, 3);   // row 13
    comprow(bufA, 3, 3);                      // row 14

    float vals[6] = {0.f, 0.f, 0.f, 0.f, 0.f, 0.f};
    #pragma unroll
    for (int i = 0; i < 4; ++i) {
        int idx = (gy0 + ty4 + i) * WW + gx0 + tx;
        float g = left[c*HW + idx];
        float aswL   = aL[i] / wg[i];
        float photoL = fabsf(g - rir[c*HW + idx]);
        float sLp = 0.5f * photoL + 0.5f * aswL;
        float aswR   = aR[i] / wg[i];
        float photoR = fabsf(right[c*HW + idx] - ril[c*HW + idx]);
        float sRp = 0.5f * photoR + 0.5f * aswR;
        float pl = pL[idx], pr = pR[idx];
        float mL = (pl > 0.5f) ? 1.f : 0.f;
        float mR = (pr > 0.5f) ? 1.f : 0.f;
        vals[0] += sLp * mL;
        vals[2] += sRp * mR;
        if (c == 0) {   // per-pixel terms counted once
            vals[1] += mL;
            vals[3] += mR;
            vals[4] += log1pf(__expf(1.f - 2.f * pl));
            vals[5] += log1pf(__expf(1.f - 2.f * pr));
        }
    }

    int lane = tid & 63, wave = tid >> 6;
    #pragma unroll
    for (int k = 0; k < 6; ++k) {
        float v = vals[k];
        #pragma unroll
        for (int off = 32; off > 0; off >>= 1) v += __shfl_down(v, off);
        if (lane == 0) red[wave][k] = v;
    }
    __syncthreads();
    if (tid == 0) {
        #pragma unroll
        for (int k = 0; k < 6; ++k) {
            float s = red[0][k] + red[1][k] + red[2][k];
            atomicAdd(&acc[k], s);
        }
    }
}

// ---------------- K4: finalize ----------------

__global__ void k_final(const float* __restrict__ acc, const float* __restrict__ weight,
                        float* __restrict__ out)
{
    float S1 = acc[0], M1 = acc[1], S2 = acc[2], M2 = acc[3], C1 = acc[4], C2 = acc[5];
    float loss_valid = S1 / (3.f * M1 + 1e-6f) + S2 / (3.f * M2 + 1e-6f);
    float loss_invalid = (C1 + C2) * (1.f / (float)HW);
    out[0] = weight[0] * (0.9f * loss_valid + 0.1f * loss_invalid);
}

// ---------------- launch ----------------

extern "C" void kernel_launch(void* const* d_in, const int* in_sizes, int n_in,
                              void* d_out, int out_size, void* d_ws, size_t ws_size,
                              hipStream_t stream)
{
    const float* left  = (const float*)d_in[0];
    const float* right = (const float*)d_in[1];
    const float* dispL = (const float*)d_in[2];
    const float* dispR = (const float*)d_in[3];
    // d_in[4] = dispmap_gt (unused), d_in[5] = brk (unused)
    const float* weight = (const float*)d_in[6];

    float* ws    = (float*)d_ws;
    float* acc   = ws;              // 8 floats (6 used)
    float* rir   = ws + 8;          // 3*HW
    float* ril   = rir + 3*HW;      // 3*HW
    float* pL    = ril + 3*HW;      // HW
    float* pR    = pL + HW;         // HW
    float* costL = pR + HW;         // 3*HW
    float* costR = costL + 3*HW;    // 3*HW

    k_resample<<<(HW + 255) / 256, 256, 0, stream>>>(left, right, dispL, dispR, rir, ril, pL, pR, acc);

    dim3 blk2(32, 8);
    dim3 grd2(WW / 32, HH / 8, 2);
    k_lcncost<<<grd2, blk2, 0, stream>>>(left, right, rir, ril, costL, costR);

    dim3 blk3(32, 2, 3);
    dim3 grd3(WW / 32, HH / 8);
    k_asw_reduce<<<grd3, blk3, 0, stream>>>(left, right, rir, ril, costL, costR, pL, pR, acc);

    k_final<<<1, 1, 0, stream>>>(acc, weight, (float*)d_out);
}

// Round 9
// 230.484 us; speedup vs baseline: 1.5327x; 1.5327x over previous
//
#include <hip/hip_runtime.h>
#include <math.h>

#define HH 480
#define WW 640
#define HW (HH*WW)

__device__ __forceinline__ unsigned bf16rne(float f) {
    unsigned u = __float_as_uint(f);
    return (u + 0x7fffu + ((u >> 16) & 1u)) >> 16;
}

// ---------------- K1: resample + photo + CE + masks ----------------

__device__ __forceinline__ float sample1(const float* __restrict__ row, float x) {
    float x0 = floorf(x);
    float w1 = x - x0;
    int xi = (int)x0;
    float v0 = (xi >= 0 && xi < WW) ? row[xi] : 0.f;
    float v1 = (xi + 1 >= 0 && xi + 1 < WW) ? row[xi + 1] : 0.f;
    return v0 * (1.f - w1) + v1 * w1;
}

__global__ __launch_bounds__(256) void k_resample(
    const float* __restrict__ left, const float* __restrict__ right,
    const float* __restrict__ dispL, const float* __restrict__ dispR,
    float* __restrict__ rir, float* __restrict__ ril,
    unsigned char* __restrict__ maskb, float* __restrict__ acc)
{
    __shared__ float red[4][6];
    int tid = threadIdx.x;
    int idx = blockIdx.x * blockDim.x + tid;
    int h = idx / WW;
    int w = idx - h * WW;
    float dL = dispL[idx];
    float dR = dispR[idx];
    float xl = (float)w - dL;   // sample right view at j - dispL
    float xr = (float)w + dR;   // sample left view  at j + dispR
    float photoL = 0.f, photoR = 0.f;
    #pragma unroll
    for (int c = 0; c < 3; ++c) {
        float rv = sample1(right + c*HW + h*WW, xl);
        float lv = sample1(left  + c*HW + h*WW, xr);
        rir[c*HW + idx] = rv;
        ril[c*HW + idx] = lv;
        photoL += fabsf(left [c*HW + idx] - rv);
        photoR += fabsf(right[c*HW + idx] - lv);
    }
    float rdr = sample1(dispR + h*WW, xl);
    float rdl = sample1(dispL + h*WW, xr);
    float pl = __expf(-0.6931f * fabsf(dL - rdr));
    float pr = __expf(-0.6931f * fabsf(dR - rdl));
    float mL = (pl > 0.5f) ? 1.f : 0.f;
    float mR = (pr > 0.5f) ? 1.f : 0.f;
    maskb[idx] = (unsigned char)((mL > 0.f ? 1u : 0u) | (mR > 0.f ? 2u : 0u));

    float vals[6];
    vals[0] = 0.5f * photoL * mL;
    vals[1] = mL;
    vals[2] = 0.5f * photoR * mR;
    vals[3] = mR;
    vals[4] = log1pf(__expf(1.f - 2.f * pl));
    vals[5] = log1pf(__expf(1.f - 2.f * pr));

    int lane = tid & 63, wave = tid >> 6;
    #pragma unroll
    for (int k = 0; k < 6; ++k) {
        float v = vals[k];
        #pragma unroll
        for (int off = 32; off > 0; off >>= 1) v += __shfl_down(v, off);
        if (lane == 0) red[wave][k] = v;
    }
    __syncthreads();
    if (tid == 0) {
        #pragma unroll
        for (int k = 0; k < 6; ++k)
            atomicAdd(&acc[k], red[0][k] + red[1][k] + red[2][k] + red[3][k]);
    }
}

// ---------------- K2: 9x9 LCN both sides (2-pass LDS reuse) + pack ----------------
// block (32,8), region 32x16 (2 output rows/thread), halo 4: raw 24x40.
// pass 0: {left, rir} -> costL, Ep/Em(left). pass 1: {right, ril} -> costR, write packed.
// packed[c*HW+idx] = uint2{ bf16(Ep)|bf16(Em)<<16, bf16(cL)|bf16(cR)<<16 }

__global__ __launch_bounds__(256) void k_lcnpack(
    const float* __restrict__ left, const float* __restrict__ right,
    const float* __restrict__ rir, const float* __restrict__ ril,
    uint2* __restrict__ packed)
{
    __shared__ float raw[6][24][40];   // 23040 B
    __shared__ float hs [6][24][32];   // 18432 B
    __shared__ float hs2[6][24][32];   // 18432 B
    int tx = threadIdx.x, ty = threadIdx.y;
    int tid = ty * 32 + tx;
    int gx0 = blockIdx.x * 32, gy0 = blockIdx.y * 16;

    float cl[2][3], epv[2][3], emv[2][3];

    #pragma unroll 1
    for (int pass = 0; pass < 2; ++pass) {
        const float* __restrict__ A = pass ? right : left;   // real (std source)
        const float* __restrict__ B = pass ? ril   : rir;    // reconstruction
        if (pass) __syncthreads();   // protect pass-0 raw/hs reads

        for (int e = tid; e < 6*24*40; e += 256) {
            int a   = e / (24*40);
            int rem = e - a * (24*40);
            int r   = rem / 40;
            int x   = rem - r * 40;
            int gy = gy0 + r - 4, gx = gx0 + x - 4;
            float v = 0.f;
            if ((unsigned)gy < (unsigned)HH && (unsigned)gx < (unsigned)WW)
                v = (a < 3) ? A[a*HW + gy*WW + gx] : B[(a-3)*HW + gy*WW + gx];
            ((float*)raw)[e] = v;
        }
        __syncthreads();

        for (int e = tid; e < 6*24*32; e += 256) {
            int a   = e / (24*32);
            int rem = e - a * (24*32);
            int r   = rem / 32;
            int x   = rem - r * 32;
            float s = 0.f, s2 = 0.f;
            #pragma unroll
            for (int dx = 0; dx < 9; ++dx) {
                float v = raw[a][r][x + dx];
                s += v;
                s2 = fmaf(v, v, s2);
            }
            ((float*)hs)[e]  = s;
            ((float*)hs2)[e] = s2;
        }
        __syncthreads();

        #pragma unroll
        for (int rr = 0; rr < 2; ++rr) {
            int yo = 2 * ty + rr;   // 0..15
            int idx = (gy0 + yo) * WW + gx0 + tx;
            #pragma unroll
            for (int c = 0; c < 3; ++c) {
                float SA = 0.f, SA2 = 0.f, SB = 0.f, SB2 = 0.f;
                #pragma unroll
                for (int dy = 0; dy < 9; ++dy) {
                    SA  += hs [c][yo + dy][tx];
                    SA2 += hs2[c][yo + dy][tx];
                    SB  += hs [3 + c][yo + dy][tx];
                    SB2 += hs2[3 + c][yo + dy][tx];
                }
                float meanA = SA * (1.f/81.f);
                float stdA  = sqrtf(fmaxf(SA2 * (1.f/81.f) - meanA * meanA, 0.f)) * (81.f/80.f);
                float lcnA  = (raw[c][yo + 4][tx + 4] - meanA) / (stdA + 1e-5f);
                float meanB = SB * (1.f/81.f);
                float stdB  = sqrtf(fmaxf(SB2 * (1.f/81.f) - meanB * meanB, 0.f)) * (81.f/80.f);
                float lcnB  = (raw[3 + c][yo + 4][tx + 4] - meanB) / (stdB + 1e-5f);
                float cost  = fabsf((lcnA - lcnB) * stdA);
                if (pass == 0) {
                    cl[rr][c] = cost;
                    float g = raw[c][yo + 4][tx + 4];
                    epv[rr][c] = __expf(0.5f * g);
                    emv[rr][c] = __expf(-0.5f * g);
                } else {
                    uint2 pk;
                    pk.x = bf16rne(epv[rr][c]) | (bf16rne(emv[rr][c]) << 16);
                    pk.y = bf16rne(cl[rr][c]) | (bf16rne(cost) << 16);
                    packed[c*HW + idx] = pk;
                }
            }
        }
    }
}

// ---------------- K3: 12x12 ASW + reduction (exp-free, slim I/O) ----------------
// block (32,4,3) = 384 threads = 6 waves; thread (tx,ty,c): channel c of 4 outputs
// (gx0+tx, gy0+4ty+i), i=0..3; region 32x16/block.
// OOB halo: g=0 => Ep=Em=1.0, costs 0 (matches zero-pad reference).
// Per tap: t = exp(-|g_c-g_q|/2) = min(Em_c*Ep_q, Ep_c*Em_q).

#define T3H 27
#define T3W 43

__global__ __launch_bounds__(384) void k_asw_reduce(
    const uint2* __restrict__ packed,
    const unsigned char* __restrict__ maskb,
    float* __restrict__ acc)
{
    __shared__ uint2 tile[3][T3H][T3W];   // 27864 B
    __shared__ float red[6][2];
    int tx = threadIdx.x, ty = threadIdx.y, c = threadIdx.z;
    int tid = tx + 32 * ty + 128 * c;
    int gx0 = blockIdx.x * 32, gy0 = blockIdx.y * 16;

    for (int e = tid; e < 3 * T3H * T3W; e += 384) {
        int cc  = e / (T3H * T3W);
        int rem = e - cc * (T3H * T3W);
        int r   = rem / T3W;
        int x   = rem - r * T3W;
        int gy = gy0 + r - 6, gx = gx0 + x - 6;
        uint2 v = make_uint2(0x3f803f80u, 0u);   // g=0: Ep=Em=1.0, costs 0
        if ((unsigned)gy < (unsigned)HH && (unsigned)gx < (unsigned)WW)
            v = packed[cc*HW + gy*WW + gx];
        tile[cc][r][x] = v;
    }
    __syncthreads();

    int ty4 = 4 * ty;
    float epc[4], emc[4];
    #pragma unroll
    for (int i = 0; i < 4; ++i) {
        unsigned vc = tile[c][ty4 + i + 6][tx + 6].x;
        epc[i] = __uint_as_float(vc << 16);
        emc[i] = __uint_as_float(vc & 0xffff0000u);
    }

    float wg[4] = {0.f,0.f,0.f,0.f}, aL[4] = {0.f,0.f,0.f,0.f}, aR[4] = {0.f,0.f,0.f,0.f};

    auto taprow = [&](int kap, int i0, int i1) {
        int r = ty4 + kap;
        #pragma unroll
        for (int dx = 0; dx < 12; ++dx) {
            uint2 v = tile[c][r][tx + dx];
            float ep = __uint_as_float(v.x << 16);
            float em = __uint_as_float(v.x & 0xffff0000u);
            float clv = __uint_as_float(v.y << 16);
            float crv = __uint_as_float(v.y & 0xffff0000u);
            #pragma unroll
            for (int i = 0; i < 4; ++i) {
                if (i >= i0 && i <= i1) {
                    float t = fminf(emc[i] * ep, epc[i] * em);
                    wg[i] += t;
                    aL[i] = fmaf(t, clv, aL[i]);
                    aR[i] = fmaf(t, crv, aR[i]);
                }
            }
        }
    };

    taprow(0, 0, 0);
    taprow(1, 0, 1);
    taprow(2, 0, 2);
    for (int kap = 3; kap <= 11; ++kap)   // rolled bulk: all 4 outputs eligible
        taprow(kap, 0, 3);
    taprow(12, 1, 3);
    taprow(13, 2, 3);
    taprow(14, 3, 3);

    float v0 = 0.f, v2 = 0.f;
    #pragma unroll
    for (int i = 0; i < 4; ++i) {
        int idx = (gy0 + ty4 + i) * WW + gx0 + tx;
        unsigned m = maskb[idx];
        float aswL = aL[i] / wg[i];
        float aswR = aR[i] / wg[i];
        if (m & 1u) v0 += 0.5f * aswL;
        if (m & 2u) v2 += 0.5f * aswR;
    }

    int lane = tid & 63, wave = tid >> 6;
    {
        float a0 = v0, a2 = v2;
        #pragma unroll
        for (int off = 32; off > 0; off >>= 1) {
            a0 += __shfl_down(a0, off);
            a2 += __shfl_down(a2, off);
        }
        if (lane == 0) { red[wave][0] = a0; red[wave][1] = a2; }
    }
    __syncthreads();
    if (tid == 0) {
        float s0 = 0.f, s2 = 0.f;
        #pragma unroll
        for (int wv = 0; wv < 6; ++wv) { s0 += red[wv][0]; s2 += red[wv][1]; }
        atomicAdd(&acc[0], s0);
        atomicAdd(&acc[2], s2);
    }
}

// ---------------- K4: finalize ----------------

__global__ void k_final(const float* __restrict__ acc, const float* __restrict__ weight,
                        float* __restrict__ out)
{
    float S1 = acc[0], M1 = acc[1], S2 = acc[2], M2 = acc[3], C1 = acc[4], C2 = acc[5];
    float loss_valid = S1 / (3.f * M1 + 1e-6f) + S2 / (3.f * M2 + 1e-6f);
    float loss_invalid = (C1 + C2) * (1.f / (float)HW);
    out[0] = weight[0] * (0.9f * loss_valid + 0.1f * loss_invalid);
}

// ---------------- launch ----------------

extern "C" void kernel_launch(void* const* d_in, const int* in_sizes, int n_in,
                              void* d_out, int out_size, void* d_ws, size_t ws_size,
                              hipStream_t stream)
{
    const float* left  = (const float*)d_in[0];
    const float* right = (const float*)d_in[1];
    const float* dispL = (const float*)d_in[2];
    const float* dispR = (const float*)d_in[3];
    // d_in[4] = dispmap_gt (unused), d_in[5] = brk (unused)
    const float* weight = (const float*)d_in[6];

    float* ws    = (float*)d_ws;
    float* acc   = ws;                       // 8 floats (6 used)
    float* rir   = ws + 8;                   // 3*HW
    float* ril   = rir + 3*HW;               // 3*HW
    uint2* packed = (uint2*)(ws + 8 + 6*HW); // 3*HW uint2
    unsigned char* maskb = (unsigned char*)(ws + 8 + 12*HW); // HW bytes

    hipMemsetAsync(acc, 0, 8 * sizeof(float), stream);

    k_resample<<<HW / 256, 256, 0, stream>>>(left, right, dispL, dispR, rir, ril, maskb, acc);

    dim3 blk2(32, 8);
    dim3 grd2(WW / 32, HH / 16);
    k_lcnpack<<<grd2, blk2, 0, stream>>>(left, right, rir, ril, packed);

    dim3 blk3(32, 4, 3);
    dim3 grd3(WW / 32, HH / 16);
    k_asw_reduce<<<grd3, blk3, 0, stream>>>(packed, maskb, acc);

    k_final<<<1, 1, 0, stream>>>(acc, weight, (float*)d_out);
}

// Round 10
// 131.165 us; speedup vs baseline: 2.6932x; 1.7572x over previous
//
#include <hip/hip_runtime.h>
#include <math.h>

#define HH 480
#define WW 640
#define HW (HH*WW)

#define NB1 1200   // K1 blocks
#define NB3 600    // K3 blocks

__device__ __forceinline__ unsigned bf16rne(float f) {
    unsigned u = __float_as_uint(f);
    return (u + 0x7fffu + ((u >> 16) & 1u)) >> 16;
}

// ---------------- K1: resample + photo + CE + masks (partials, no atomics) ----------------

__device__ __forceinline__ float sample1(const float* __restrict__ row, float x) {
    float x0 = floorf(x);
    float w1 = x - x0;
    int xi = (int)x0;
    float v0 = (xi >= 0 && xi < WW) ? row[xi] : 0.f;
    float v1 = (xi + 1 >= 0 && xi + 1 < WW) ? row[xi + 1] : 0.f;
    return v0 * (1.f - w1) + v1 * w1;
}

__global__ __launch_bounds__(256) void k_resample(
    const float* __restrict__ left, const float* __restrict__ right,
    const float* __restrict__ dispL, const float* __restrict__ dispR,
    float* __restrict__ rir, float* __restrict__ ril,
    unsigned char* __restrict__ maskb, float* __restrict__ part1)
{
    __shared__ float red[4][6];
    int tid = threadIdx.x;
    int idx = blockIdx.x * blockDim.x + tid;
    int h = idx / WW;
    int w = idx - h * WW;
    float dL = dispL[idx];
    float dR = dispR[idx];
    float xl = (float)w - dL;   // sample right view at j - dispL
    float xr = (float)w + dR;   // sample left view  at j + dispR
    float photoL = 0.f, photoR = 0.f;
    #pragma unroll
    for (int c = 0; c < 3; ++c) {
        float rv = sample1(right + c*HW + h*WW, xl);
        float lv = sample1(left  + c*HW + h*WW, xr);
        rir[c*HW + idx] = rv;
        ril[c*HW + idx] = lv;
        photoL += fabsf(left [c*HW + idx] - rv);
        photoR += fabsf(right[c*HW + idx] - lv);
    }
    float rdr = sample1(dispR + h*WW, xl);
    float rdl = sample1(dispL + h*WW, xr);
    float pl = __expf(-0.6931f * fabsf(dL - rdr));
    float pr = __expf(-0.6931f * fabsf(dR - rdl));
    float mL = (pl > 0.5f) ? 1.f : 0.f;
    float mR = (pr > 0.5f) ? 1.f : 0.f;
    maskb[idx] = (unsigned char)((mL > 0.f ? 1u : 0u) | (mR > 0.f ? 2u : 0u));

    float vals[6];
    vals[0] = 0.5f * photoL * mL;
    vals[1] = mL;
    vals[2] = 0.5f * photoR * mR;
    vals[3] = mR;
    vals[4] = log1pf(__expf(1.f - 2.f * pl));
    vals[5] = log1pf(__expf(1.f - 2.f * pr));

    int lane = tid & 63, wave = tid >> 6;
    #pragma unroll
    for (int k = 0; k < 6; ++k) {
        float v = vals[k];
        #pragma unroll
        for (int off = 32; off > 0; off >>= 1) v += __shfl_down(v, off);
        if (lane == 0) red[wave][k] = v;
    }
    __syncthreads();
    if (tid < 6)
        part1[blockIdx.x * 8 + tid] =
            red[0][tid] + red[1][tid] + red[2][tid] + red[3][tid];
}

// ---------------- K2: 9x9 LCN both sides (2-pass LDS reuse) + pack ----------------
// block (32,8), region 32x16 (2 output rows/thread), halo 4: raw 24x40.
// pass 0: {left, rir} -> costL, Ep/Em(left). pass 1: {right, ril} -> costR, write packed.
// packed[c*HW+idx] = uint2{ bf16(Ep)|bf16(Em)<<16, bf16(cL)|bf16(cR)<<16 }

__global__ __launch_bounds__(256) void k_lcnpack(
    const float* __restrict__ left, const float* __restrict__ right,
    const float* __restrict__ rir, const float* __restrict__ ril,
    uint2* __restrict__ packed)
{
    __shared__ float raw[6][24][40];   // 23040 B
    __shared__ float hs [6][24][32];   // 18432 B
    __shared__ float hs2[6][24][32];   // 18432 B
    int tx = threadIdx.x, ty = threadIdx.y;
    int tid = ty * 32 + tx;
    int gx0 = blockIdx.x * 32, gy0 = blockIdx.y * 16;

    float cl[2][3], epv[2][3], emv[2][3];

    #pragma unroll 1
    for (int pass = 0; pass < 2; ++pass) {
        const float* __restrict__ A = pass ? right : left;   // real (std source)
        const float* __restrict__ B = pass ? ril   : rir;    // reconstruction
        if (pass) __syncthreads();   // protect pass-0 raw/hs reads

        for (int e = tid; e < 6*24*40; e += 256) {
            int a   = e / (24*40);
            int rem = e - a * (24*40);
            int r   = rem / 40;
            int x   = rem - r * 40;
            int gy = gy0 + r - 4, gx = gx0 + x - 4;
            float v = 0.f;
            if ((unsigned)gy < (unsigned)HH && (unsigned)gx < (unsigned)WW)
                v = (a < 3) ? A[a*HW + gy*WW + gx] : B[(a-3)*HW + gy*WW + gx];
            ((float*)raw)[e] = v;
        }
        __syncthreads();

        for (int e = tid; e < 6*24*32; e += 256) {
            int a   = e / (24*32);
            int rem = e - a * (24*32);
            int r   = rem / 32;
            int x   = rem - r * 32;
            float s = 0.f, s2 = 0.f;
            #pragma unroll
            for (int dx = 0; dx < 9; ++dx) {
                float v = raw[a][r][x + dx];
                s += v;
                s2 = fmaf(v, v, s2);
            }
            ((float*)hs)[e]  = s;
            ((float*)hs2)[e] = s2;
        }
        __syncthreads();

        #pragma unroll
        for (int rr = 0; rr < 2; ++rr) {
            int yo = 2 * ty + rr;   // 0..15
            int idx = (gy0 + yo) * WW + gx0 + tx;
            #pragma unroll
            for (int c = 0; c < 3; ++c) {
                float SA = 0.f, SA2 = 0.f, SB = 0.f, SB2 = 0.f;
                #pragma unroll
                for (int dy = 0; dy < 9; ++dy) {
                    SA  += hs [c][yo + dy][tx];
                    SA2 += hs2[c][yo + dy][tx];
                    SB  += hs [3 + c][yo + dy][tx];
                    SB2 += hs2[3 + c][yo + dy][tx];
                }
                float meanA = SA * (1.f/81.f);
                float stdA  = sqrtf(fmaxf(SA2 * (1.f/81.f) - meanA * meanA, 0.f)) * (81.f/80.f);
                float lcnA  = (raw[c][yo + 4][tx + 4] - meanA) / (stdA + 1e-5f);
                float meanB = SB * (1.f/81.f);
                float stdB  = sqrtf(fmaxf(SB2 * (1.f/81.f) - meanB * meanB, 0.f)) * (81.f/80.f);
                float lcnB  = (raw[3 + c][yo + 4][tx + 4] - meanB) / (stdB + 1e-5f);
                float cost  = fabsf((lcnA - lcnB) * stdA);
                if (pass == 0) {
                    cl[rr][c] = cost;
                    float g = raw[c][yo + 4][tx + 4];
                    epv[rr][c] = __expf(0.5f * g);
                    emv[rr][c] = __expf(-0.5f * g);
                } else {
                    uint2 pk;
                    pk.x = bf16rne(epv[rr][c]) | (bf16rne(emv[rr][c]) << 16);
                    pk.y = bf16rne(cl[rr][c]) | (bf16rne(cost) << 16);
                    packed[c*HW + idx] = pk;
                }
            }
        }
    }
}

// ---------------- K3: 12x12 ASW + reduction (exp-free, slim I/O, partials) ----------------
// block (32,4,3) = 384 threads = 6 waves; thread (tx,ty,c): channel c of 4 outputs
// (gx0+tx, gy0+4ty+i), i=0..3; region 32x16/block.
// OOB halo: g=0 => Ep=Em=1.0, costs 0 (matches zero-pad reference).
// Per tap: t = exp(-|g_c-g_q|/2) = min(Em_c*Ep_q, Ep_c*Em_q).

#define T3H 27
#define T3W 43

__global__ __launch_bounds__(384) void k_asw_reduce(
    const uint2* __restrict__ packed,
    const unsigned char* __restrict__ maskb,
    float* __restrict__ part3)
{
    __shared__ uint2 tile[3][T3H][T3W];   // 27864 B
    __shared__ float red[6][2];
    int tx = threadIdx.x, ty = threadIdx.y, c = threadIdx.z;
    int tid = tx + 32 * ty + 128 * c;
    int gx0 = blockIdx.x * 32, gy0 = blockIdx.y * 16;

    for (int e = tid; e < 3 * T3H * T3W; e += 384) {
        int cc  = e / (T3H * T3W);
        int rem = e - cc * (T3H * T3W);
        int r   = rem / T3W;
        int x   = rem - r * T3W;
        int gy = gy0 + r - 6, gx = gx0 + x - 6;
        uint2 v = make_uint2(0x3f803f80u, 0u);   // g=0: Ep=Em=1.0, costs 0
        if ((unsigned)gy < (unsigned)HH && (unsigned)gx < (unsigned)WW)
            v = packed[cc*HW + gy*WW + gx];
        tile[cc][r][x] = v;
    }
    __syncthreads();

    int ty4 = 4 * ty;
    float epc[4], emc[4];
    #pragma unroll
    for (int i = 0; i < 4; ++i) {
        unsigned vc = tile[c][ty4 + i + 6][tx + 6].x;
        epc[i] = __uint_as_float(vc << 16);
        emc[i] = __uint_as_float(vc & 0xffff0000u);
    }

    float wg[4] = {0.f,0.f,0.f,0.f}, aL[4] = {0.f,0.f,0.f,0.f}, aR[4] = {0.f,0.f,0.f,0.f};

    auto taprow = [&](int kap, int i0, int i1) {
        int r = ty4 + kap;
        #pragma unroll
        for (int dx = 0; dx < 12; ++dx) {
            uint2 v = tile[c][r][tx + dx];
            float ep = __uint_as_float(v.x << 16);
            float em = __uint_as_float(v.x & 0xffff0000u);
            float clv = __uint_as_float(v.y << 16);
            float crv = __uint_as_float(v.y & 0xffff0000u);
            #pragma unroll
            for (int i = 0; i < 4; ++i) {
                if (i >= i0 && i <= i1) {
                    float t = fminf(emc[i] * ep, epc[i] * em);
                    wg[i] += t;
                    aL[i] = fmaf(t, clv, aL[i]);
                    aR[i] = fmaf(t, crv, aR[i]);
                }
            }
        }
    };

    taprow(0, 0, 0);
    taprow(1, 0, 1);
    taprow(2, 0, 2);
    for (int kap = 3; kap <= 11; ++kap)   // rolled bulk: all 4 outputs eligible
        taprow(kap, 0, 3);
    taprow(12, 1, 3);
    taprow(13, 2, 3);
    taprow(14, 3, 3);

    float v0 = 0.f, v2 = 0.f;
    #pragma unroll
    for (int i = 0; i < 4; ++i) {
        int idx = (gy0 + ty4 + i) * WW + gx0 + tx;
        unsigned m = maskb[idx];
        float aswL = aL[i] / wg[i];
        float aswR = aR[i] / wg[i];
        if (m & 1u) v0 += 0.5f * aswL;
        if (m & 2u) v2 += 0.5f * aswR;
    }

    int lane = tid & 63, wave = tid >> 6;
    {
        float a0 = v0, a2 = v2;
        #pragma unroll
        for (int off = 32; off > 0; off >>= 1) {
            a0 += __shfl_down(a0, off);
            a2 += __shfl_down(a2, off);
        }
        if (lane == 0) { red[wave][0] = a0; red[wave][1] = a2; }
    }
    __syncthreads();
    if (tid == 0) {
        float s0 = 0.f, s2 = 0.f;
        #pragma unroll
        for (int wv = 0; wv < 6; ++wv) { s0 += red[wv][0]; s2 += red[wv][1]; }
        int bid = blockIdx.y * gridDim.x + blockIdx.x;
        part3[bid * 8 + 0] = s0;
        part3[bid * 8 + 1] = s2;
    }
}

// ---------------- K4: reduce partials + finalize ----------------

__global__ __launch_bounds__(256) void k_final(
    const float* __restrict__ part1, const float* __restrict__ part3,
    const float* __restrict__ weight, float* __restrict__ out)
{
    __shared__ float red[4][6];
    int tid = threadIdx.x;
    float v[6] = {0.f, 0.f, 0.f, 0.f, 0.f, 0.f};
    for (int b = tid; b < NB1; b += 256) {
        #pragma unroll
        for (int k = 0; k < 6; ++k) v[k] += part1[b * 8 + k];
    }
    for (int b = tid; b < NB3; b += 256) {
        v[0] += part3[b * 8 + 0];
        v[2] += part3[b * 8 + 1];
    }
    int lane = tid & 63, wave = tid >> 6;
    #pragma unroll
    for (int k = 0; k < 6; ++k) {
        float s = v[k];
        #pragma unroll
        for (int off = 32; off > 0; off >>= 1) s += __shfl_down(s, off);
        if (lane == 0) red[wave][k] = s;
    }
    __syncthreads();
    if (tid == 0) {
        float a[6];
        #pragma unroll
        for (int k = 0; k < 6; ++k)
            a[k] = red[0][k] + red[1][k] + red[2][k] + red[3][k];
        float loss_valid = a[0] / (3.f * a[1] + 1e-6f) + a[2] / (3.f * a[3] + 1e-6f);
        float loss_invalid = (a[4] + a[5]) * (1.f / (float)HW);
        out[0] = weight[0] * (0.9f * loss_valid + 0.1f * loss_invalid);
    }
}

// ---------------- launch ----------------

extern "C" void kernel_launch(void* const* d_in, const int* in_sizes, int n_in,
                              void* d_out, int out_size, void* d_ws, size_t ws_size,
                              hipStream_t stream)
{
    const float* left  = (const float*)d_in[0];
    const float* right = (const float*)d_in[1];
    const float* dispL = (const float*)d_in[2];
    const float* dispR = (const float*)d_in[3];
    // d_in[4] = dispmap_gt (unused), d_in[5] = brk (unused)
    const float* weight = (const float*)d_in[6];

    float* ws    = (float*)d_ws;
    float* rir   = ws;                        // 3*HW
    float* ril   = rir + 3*HW;                // 3*HW
    uint2* packed = (uint2*)(ws + 6*HW);      // 3*HW uint2 (6*HW floats)
    unsigned char* maskb = (unsigned char*)(ws + 12*HW);  // HW bytes
    float* part1 = ws + 12*HW + HW/4;         // NB1*8
    float* part3 = part1 + NB1*8;             // NB3*8

    k_resample<<<NB1, 256, 0, stream>>>(left, right, dispL, dispR, rir, ril, maskb, part1);

    dim3 blk2(32, 8);
    dim3 grd2(WW / 32, HH / 16);
    k_lcnpack<<<grd2, blk2, 0, stream>>>(left, right, rir, ril, packed);

    dim3 blk3(32, 4, 3);
    dim3 grd3(WW / 32, HH / 16);
    k_asw_reduce<<<grd3, blk3, 0, stream>>>(packed, maskb, part3);

    k_final<<<1, 256, 0, stream>>>(part1, part3, weight, (float*)d_out);
}

// Round 11
// 106.745 us; speedup vs baseline: 3.3093x; 1.2288x over previous
//
#include <hip/hip_runtime.h>
#include <math.h>

#define HH 480
#define WW 640
#define HW (HH*WW)

#define NB1 1200   // K1 blocks
#define NB3 600    // K3 blocks

__device__ __forceinline__ unsigned bf16rne(float f) {
    unsigned u = __float_as_uint(f);
    return (u + 0x7fffu + ((u >> 16) & 1u)) >> 16;
}

// ---------------- K1: resample + photo + CE + masks (partials, no atomics) ----------------

__device__ __forceinline__ float sample1(const float* __restrict__ row, float x) {
    float x0 = floorf(x);
    float w1 = x - x0;
    int xi = (int)x0;
    float v0 = (xi >= 0 && xi < WW) ? row[xi] : 0.f;
    float v1 = (xi + 1 >= 0 && xi + 1 < WW) ? row[xi + 1] : 0.f;
    return v0 * (1.f - w1) + v1 * w1;
}

__global__ __launch_bounds__(256) void k_resample(
    const float* __restrict__ left, const float* __restrict__ right,
    const float* __restrict__ dispL, const float* __restrict__ dispR,
    float* __restrict__ rir, float* __restrict__ ril,
    unsigned char* __restrict__ maskb, float* __restrict__ part1)
{
    __shared__ float red[4][6];
    int tid = threadIdx.x;
    int idx = blockIdx.x * blockDim.x + tid;
    int h = idx / WW;
    int w = idx - h * WW;
    float dL = dispL[idx];
    float dR = dispR[idx];
    float xl = (float)w - dL;   // sample right view at j - dispL
    float xr = (float)w + dR;   // sample left view  at j + dispR
    float photoL = 0.f, photoR = 0.f;
    #pragma unroll
    for (int c = 0; c < 3; ++c) {
        float rv = sample1(right + c*HW + h*WW, xl);
        float lv = sample1(left  + c*HW + h*WW, xr);
        rir[c*HW + idx] = rv;
        ril[c*HW + idx] = lv;
        photoL += fabsf(left [c*HW + idx] - rv);
        photoR += fabsf(right[c*HW + idx] - lv);
    }
    float rdr = sample1(dispR + h*WW, xl);
    float rdl = sample1(dispL + h*WW, xr);
    float pl = __expf(-0.6931f * fabsf(dL - rdr));
    float pr = __expf(-0.6931f * fabsf(dR - rdl));
    float mL = (pl > 0.5f) ? 1.f : 0.f;
    float mR = (pr > 0.5f) ? 1.f : 0.f;
    maskb[idx] = (unsigned char)((mL > 0.f ? 1u : 0u) | (mR > 0.f ? 2u : 0u));

    float vals[6];
    vals[0] = 0.5f * photoL * mL;
    vals[1] = mL;
    vals[2] = 0.5f * photoR * mR;
    vals[3] = mR;
    vals[4] = log1pf(__expf(1.f - 2.f * pl));
    vals[5] = log1pf(__expf(1.f - 2.f * pr));

    int lane = tid & 63, wave = tid >> 6;
    #pragma unroll
    for (int k = 0; k < 6; ++k) {
        float v = vals[k];
        #pragma unroll
        for (int off = 32; off > 0; off >>= 1) v += __shfl_down(v, off);
        if (lane == 0) red[wave][k] = v;
    }
    __syncthreads();
    if (tid < 6)
        part1[blockIdx.x * 8 + tid] =
            red[0][tid] + red[1][tid] + red[2][tid] + red[3][tid];
}

// ---------------- K2: 9x9 LCN (separable), one side per blockIdx.z, packed outputs ----------------
// block (32,8), region 32x8, halo 4: raw 16x40; grid (20,60,2) = 2400 blocks.
// z=0: A=left,  B=rir -> costL (bf16 cl16), Ep/Em(left) packed into epem.
// z=1: A=right, B=ril -> costR (bf16 cr16).

__global__ __launch_bounds__(256) void k_lcnpack(
    const float* __restrict__ left, const float* __restrict__ right,
    const float* __restrict__ rir, const float* __restrict__ ril,
    unsigned* __restrict__ epem,
    unsigned short* __restrict__ cl16, unsigned short* __restrict__ cr16)
{
    __shared__ float raw[6][16][40];   // 15360 B
    __shared__ float hs [6][16][32];   // 12288 B
    __shared__ float hs2[6][16][32];   // 12288 B
    int tx = threadIdx.x, ty = threadIdx.y;
    int tid = ty * 32 + tx;
    int gx0 = blockIdx.x * 32, gy0 = blockIdx.y * 8;
    const float* __restrict__ A = blockIdx.z ? right : left;   // real image (std source)
    const float* __restrict__ B = blockIdx.z ? ril   : rir;    // reconstruction

    for (int e = tid; e < 6*16*40; e += 256) {
        int a   = e / (16*40);
        int rem = e - a * (16*40);
        int r   = rem / 40;
        int x   = rem - r * 40;
        int gy = gy0 + r - 4, gx = gx0 + x - 4;
        float v = 0.f;
        if ((unsigned)gy < (unsigned)HH && (unsigned)gx < (unsigned)WW)
            v = (a < 3) ? A[a*HW + gy*WW + gx] : B[(a-3)*HW + gy*WW + gx];
        ((float*)raw)[e] = v;
    }
    __syncthreads();

    for (int e = tid; e < 6*16*32; e += 256) {
        int a   = e / (16*32);
        int rem = e - a * (16*32);
        int r   = rem / 32;
        int x   = rem - r * 32;
        float s = 0.f, s2 = 0.f;
        #pragma unroll
        for (int dx = 0; dx < 9; ++dx) {
            float v = raw[a][r][x + dx];
            s += v;
            s2 = fmaf(v, v, s2);
        }
        ((float*)hs)[e]  = s;
        ((float*)hs2)[e] = s2;
    }
    __syncthreads();

    int idx = (gy0 + ty) * WW + gx0 + tx;
    #pragma unroll
    for (int c = 0; c < 3; ++c) {
        float SA = 0.f, SA2 = 0.f, SB = 0.f, SB2 = 0.f;
        #pragma unroll
        for (int dy = 0; dy < 9; ++dy) {
            SA  += hs [c][ty + dy][tx];
            SA2 += hs2[c][ty + dy][tx];
            SB  += hs [3 + c][ty + dy][tx];
            SB2 += hs2[3 + c][ty + dy][tx];
        }
        float meanA = SA * (1.f/81.f);
        float stdA  = sqrtf(fmaxf(SA2 * (1.f/81.f) - meanA * meanA, 0.f)) * (81.f/80.f);
        float lcnA  = (raw[c][ty + 4][tx + 4] - meanA) / (stdA + 1e-5f);
        float meanB = SB * (1.f/81.f);
        float stdB  = sqrtf(fmaxf(SB2 * (1.f/81.f) - meanB * meanB, 0.f)) * (81.f/80.f);
        float lcnB  = (raw[3 + c][ty + 4][tx + 4] - meanB) / (stdB + 1e-5f);
        float cost  = fabsf((lcnA - lcnB) * stdA);
        if (blockIdx.z == 0) {
            float g = raw[c][ty + 4][tx + 4];
            epem[c*HW + idx] = bf16rne(__expf(0.5f * g)) | (bf16rne(__expf(-0.5f * g)) << 16);
            cl16[c*HW + idx] = (unsigned short)bf16rne(cost);
        } else {
            cr16[c*HW + idx] = (unsigned short)bf16rne(cost);
        }
    }
}

// ---------------- K3: 12x12 ASW + reduction (exp-free, slim I/O, partials) ----------------
// block (32,4,3) = 384 threads = 6 waves; thread (tx,ty,c): channel c of 4 outputs
// (gx0+tx, gy0+4ty+i), i=0..3; region 32x16/block.
// Tile uint2: .x = bf16(Ep)|bf16(Em)<<16; .y = bf16(costL)|bf16(costR)<<16.
// OOB halo: g=0 => Ep=Em=1.0, costs 0 (matches zero-pad reference).
// Per tap: t = exp(-|g_c-g_q|/2) = min(Em_c*Ep_q, Ep_c*Em_q).

#define T3H 27
#define T3W 43

__global__ __launch_bounds__(384) void k_asw_reduce(
    const unsigned* __restrict__ epem,
    const unsigned short* __restrict__ cl16, const unsigned short* __restrict__ cr16,
    const unsigned char* __restrict__ maskb,
    float* __restrict__ part3)
{
    __shared__ uint2 tile[3][T3H][T3W];   // 27864 B
    __shared__ float red[6][2];
    int tx = threadIdx.x, ty = threadIdx.y, c = threadIdx.z;
    int tid = tx + 32 * ty + 128 * c;
    int gx0 = blockIdx.x * 32, gy0 = blockIdx.y * 16;

    for (int e = tid; e < 3 * T3H * T3W; e += 384) {
        int cc  = e / (T3H * T3W);
        int rem = e - cc * (T3H * T3W);
        int r   = rem / T3W;
        int x   = rem - r * T3W;
        int gy = gy0 + r - 6, gx = gx0 + x - 6;
        uint2 v = make_uint2(0x3f803f80u, 0u);   // g=0: Ep=Em=1.0, costs 0
        if ((unsigned)gy < (unsigned)HH && (unsigned)gx < (unsigned)WW) {
            int o = cc*HW + gy*WW + gx;
            v.x = epem[o];
            v.y = (unsigned)cl16[o] | ((unsigned)cr16[o] << 16);
        }
        tile[cc][r][x] = v;
    }
    __syncthreads();

    int ty4 = 4 * ty;
    float epc[4], emc[4];
    #pragma unroll
    for (int i = 0; i < 4; ++i) {
        unsigned vc = tile[c][ty4 + i + 6][tx + 6].x;
        epc[i] = __uint_as_float(vc << 16);
        emc[i] = __uint_as_float(vc & 0xffff0000u);
    }

    float wg[4] = {0.f,0.f,0.f,0.f}, aL[4] = {0.f,0.f,0.f,0.f}, aR[4] = {0.f,0.f,0.f,0.f};

    auto taprow = [&](int kap, int i0, int i1) {
        int r = ty4 + kap;
        #pragma unroll
        for (int dx = 0; dx < 12; ++dx) {
            uint2 v = tile[c][r][tx + dx];
            float ep = __uint_as_float(v.x << 16);
            float em = __uint_as_float(v.x & 0xffff0000u);
            float clv = __uint_as_float(v.y << 16);
            float crv = __uint_as_float(v.y & 0xffff0000u);
            #pragma unroll
            for (int i = 0; i < 4; ++i) {
                if (i >= i0 && i <= i1) {
                    float t = fminf(emc[i] * ep, epc[i] * em);
                    wg[i] += t;
                    aL[i] = fmaf(t, clv, aL[i]);
                    aR[i] = fmaf(t, crv, aR[i]);
                }
            }
        }
    };

    taprow(0, 0, 0);
    taprow(1, 0, 1);
    taprow(2, 0, 2);
    for (int kap = 3; kap <= 11; ++kap)   // rolled bulk: all 4 outputs eligible
        taprow(kap, 0, 3);
    taprow(12, 1, 3);
    taprow(13, 2, 3);
    taprow(14, 3, 3);

    float v0 = 0.f, v2 = 0.f;
    #pragma unroll
    for (int i = 0; i < 4; ++i) {
        int idx = (gy0 + ty4 + i) * WW + gx0 + tx;
        unsigned m = maskb[idx];
        float aswL = aL[i] / wg[i];
        float aswR = aR[i] / wg[i];
        if (m & 1u) v0 += 0.5f * aswL;
        if (m & 2u) v2 += 0.5f * aswR;
    }

    int lane = tid & 63, wave = tid >> 6;
    {
        float a0 = v0, a2 = v2;
        #pragma unroll
        for (int off = 32; off > 0; off >>= 1) {
            a0 += __shfl_down(a0, off);
            a2 += __shfl_down(a2, off);
        }
        if (lane == 0) { red[wave][0] = a0; red[wave][1] = a2; }
    }
    __syncthreads();
    if (tid == 0) {
        float s0 = 0.f, s2 = 0.f;
        #pragma unroll
        for (int wv = 0; wv < 6; ++wv) { s0 += red[wv][0]; s2 += red[wv][1]; }
        int bid = blockIdx.y * gridDim.x + blockIdx.x;
        part3[bid * 8 + 0] = s0;
        part3[bid * 8 + 1] = s2;
    }
}

// ---------------- K4: reduce partials + finalize ----------------

__global__ __launch_bounds__(256) void k_final(
    const float* __restrict__ part1, const float* __restrict__ part3,
    const float* __restrict__ weight, float* __restrict__ out)
{
    __shared__ float red[4][6];
    int tid = threadIdx.x;
    float v[6] = {0.f, 0.f, 0.f, 0.f, 0.f, 0.f};
    for (int b = tid; b < NB1; b += 256) {
        #pragma unroll
        for (int k = 0; k < 6; ++k) v[k] += part1[b * 8 + k];
    }
    for (int b = tid; b < NB3; b += 256) {
        v[0] += part3[b * 8 + 0];
        v[2] += part3[b * 8 + 1];
    }
    int lane = tid & 63, wave = tid >> 6;
    #pragma unroll
    for (int k = 0; k < 6; ++k) {
        float s = v[k];
        #pragma unroll
        for (int off = 32; off > 0; off >>= 1) s += __shfl_down(s, off);
        if (lane == 0) red[wave][k] = s;
    }
    __syncthreads();
    if (tid == 0) {
        float a[6];
        #pragma unroll
        for (int k = 0; k < 6; ++k)
            a[k] = red[0][k] + red[1][k] + red[2][k] + red[3][k];
        float loss_valid = a[0] / (3.f * a[1] + 1e-6f) + a[2] / (3.f * a[3] + 1e-6f);
        float loss_invalid = (a[4] + a[5]) * (1.f / (float)HW);
        out[0] = weight[0] * (0.9f * loss_valid + 0.1f * loss_invalid);
    }
}

// ---------------- launch ----------------

extern "C" void kernel_launch(void* const* d_in, const int* in_sizes, int n_in,
                              void* d_out, int out_size, void* d_ws, size_t ws_size,
                              hipStream_t stream)
{
    const float* left  = (const float*)d_in[0];
    const float* right = (const float*)d_in[1];
    const float* dispL = (const float*)d_in[2];
    const float* dispR = (const float*)d_in[3];
    // d_in[4] = dispmap_gt (unused), d_in[5] = brk (unused)
    const float* weight = (const float*)d_in[6];

    float* ws    = (float*)d_ws;
    float* rir   = ws;                                  // 3*HW f32
    float* ril   = rir + 3*HW;                          // 3*HW f32
    unsigned* epem = (unsigned*)(ws + 6*HW);            // 3*HW u32
    unsigned short* cl16 = (unsigned short*)(ws + 9*HW);            // 3*HW u16
    unsigned short* cr16 = (unsigned short*)(ws + 9*HW) + 3*HW;     // 3*HW u16
    unsigned char* maskb = (unsigned char*)(ws + 12*HW);            // HW bytes
    float* part1 = ws + 12*HW + HW/4;                   // NB1*8
    float* part3 = part1 + NB1*8;                       // NB3*8

    k_resample<<<NB1, 256, 0, stream>>>(left, right, dispL, dispR, rir, ril, maskb, part1);

    dim3 blk2(32, 8);
    dim3 grd2(WW / 32, HH / 8, 2);
    k_lcnpack<<<grd2, blk2, 0, stream>>>(left, right, rir, ril, epem, cl16, cr16);

    dim3 blk3(32, 4, 3);
    dim3 grd3(WW / 32, HH / 16);
    k_asw_reduce<<<grd3, blk3, 0, stream>>>(epem, cl16, cr16, maskb, part3);

    k_final<<<1, 256, 0, stream>>>(part1, part3, weight, (float*)d_out);
}

// Round 12
// 91.201 us; speedup vs baseline: 3.8734x; 1.1704x over previous
//
#include <hip/hip_runtime.h>
#include <math.h>

#define HH 480
#define WW 640
#define HW (HH*WW)

#define NB1 1200   // K1 blocks
#define NB3 1800   // K3 blocks (20 x 30 x 3)

__device__ __forceinline__ unsigned bf16rne(float f) {
    unsigned u = __float_as_uint(f);
    return (u + 0x7fffu + ((u >> 16) & 1u)) >> 16;
}

// ---------------- K1: resample + photo + CE + masks (partials, no atomics) ----------------

__device__ __forceinline__ float sample1(const float* __restrict__ row, float x) {
    float x0 = floorf(x);
    float w1 = x - x0;
    int xi = (int)x0;
    float v0 = (xi >= 0 && xi < WW) ? row[xi] : 0.f;
    float v1 = (xi + 1 >= 0 && xi + 1 < WW) ? row[xi + 1] : 0.f;
    return v0 * (1.f - w1) + v1 * w1;
}

__global__ __launch_bounds__(256) void k_resample(
    const float* __restrict__ left, const float* __restrict__ right,
    const float* __restrict__ dispL, const float* __restrict__ dispR,
    float* __restrict__ rir, float* __restrict__ ril,
    unsigned char* __restrict__ maskb, float* __restrict__ part1)
{
    __shared__ float red[4][6];
    int tid = threadIdx.x;
    int idx = blockIdx.x * blockDim.x + tid;
    int h = idx / WW;
    int w = idx - h * WW;
    float dL = dispL[idx];
    float dR = dispR[idx];
    float xl = (float)w - dL;   // sample right view at j - dispL
    float xr = (float)w + dR;   // sample left view  at j + dispR
    float photoL = 0.f, photoR = 0.f;
    #pragma unroll
    for (int c = 0; c < 3; ++c) {
        float rv = sample1(right + c*HW + h*WW, xl);
        float lv = sample1(left  + c*HW + h*WW, xr);
        rir[c*HW + idx] = rv;
        ril[c*HW + idx] = lv;
        photoL += fabsf(left [c*HW + idx] - rv);
        photoR += fabsf(right[c*HW + idx] - lv);
    }
    float rdr = sample1(dispR + h*WW, xl);
    float rdl = sample1(dispL + h*WW, xr);
    float pl = __expf(-0.6931f * fabsf(dL - rdr));
    float pr = __expf(-0.6931f * fabsf(dR - rdl));
    float mL = (pl > 0.5f) ? 1.f : 0.f;
    float mR = (pr > 0.5f) ? 1.f : 0.f;
    maskb[idx] = (unsigned char)((mL > 0.f ? 1u : 0u) | (mR > 0.f ? 2u : 0u));

    float vals[6];
    vals[0] = 0.5f * photoL * mL;
    vals[1] = mL;
    vals[2] = 0.5f * photoR * mR;
    vals[3] = mR;
    vals[4] = log1pf(__expf(1.f - 2.f * pl));
    vals[5] = log1pf(__expf(1.f - 2.f * pr));

    int lane = tid & 63, wave = tid >> 6;
    #pragma unroll
    for (int k = 0; k < 6; ++k) {
        float v = vals[k];
        #pragma unroll
        for (int off = 32; off > 0; off >>= 1) v += __shfl_down(v, off);
        if (lane == 0) red[wave][k] = v;
    }
    __syncthreads();
    if (tid < 6)
        part1[blockIdx.x * 8 + tid] =
            red[0][tid] + red[1][tid] + red[2][tid] + red[3][tid];
}

// ---------------- K2: 9x9 LCN (separable), one side per blockIdx.z, packed outputs ----------------
// block (32,8), region 32x8, halo 4: raw 16x40; grid (20,60,2) = 2400 blocks.
// z=0: A=left,  B=rir -> costL (bf16 cl16), Ep/Em(left) packed into epem.
// z=1: A=right, B=ril -> costR (bf16 cr16).

__global__ __launch_bounds__(256) void k_lcnpack(
    const float* __restrict__ left, const float* __restrict__ right,
    const float* __restrict__ rir, const float* __restrict__ ril,
    unsigned* __restrict__ epem,
    unsigned short* __restrict__ cl16, unsigned short* __restrict__ cr16)
{
    __shared__ float raw[6][16][40];   // 15360 B
    __shared__ float hs [6][16][32];   // 12288 B
    __shared__ float hs2[6][16][32];   // 12288 B
    int tx = threadIdx.x, ty = threadIdx.y;
    int tid = ty * 32 + tx;
    int gx0 = blockIdx.x * 32, gy0 = blockIdx.y * 8;
    const float* __restrict__ A = blockIdx.z ? right : left;   // real image (std source)
    const float* __restrict__ B = blockIdx.z ? ril   : rir;    // reconstruction

    for (int e = tid; e < 6*16*40; e += 256) {
        int a   = e / (16*40);
        int rem = e - a * (16*40);
        int r   = rem / 40;
        int x   = rem - r * 40;
        int gy = gy0 + r - 4, gx = gx0 + x - 4;
        float v = 0.f;
        if ((unsigned)gy < (unsigned)HH && (unsigned)gx < (unsigned)WW)
            v = (a < 3) ? A[a*HW + gy*WW + gx] : B[(a-3)*HW + gy*WW + gx];
        ((float*)raw)[e] = v;
    }
    __syncthreads();

    for (int e = tid; e < 6*16*32; e += 256) {
        int a   = e / (16*32);
        int rem = e - a * (16*32);
        int r   = rem / 32;
        int x   = rem - r * 32;
        float s = 0.f, s2 = 0.f;
        #pragma unroll
        for (int dx = 0; dx < 9; ++dx) {
            float v = raw[a][r][x + dx];
            s += v;
            s2 = fmaf(v, v, s2);
        }
        ((float*)hs)[e]  = s;
        ((float*)hs2)[e] = s2;
    }
    __syncthreads();

    int idx = (gy0 + ty) * WW + gx0 + tx;
    #pragma unroll
    for (int c = 0; c < 3; ++c) {
        float SA = 0.f, SA2 = 0.f, SB = 0.f, SB2 = 0.f;
        #pragma unroll
        for (int dy = 0; dy < 9; ++dy) {
            SA  += hs [c][ty + dy][tx];
            SA2 += hs2[c][ty + dy][tx];
            SB  += hs [3 + c][ty + dy][tx];
            SB2 += hs2[3 + c][ty + dy][tx];
        }
        float meanA = SA * (1.f/81.f);
        float stdA  = sqrtf(fmaxf(SA2 * (1.f/81.f) - meanA * meanA, 0.f)) * (81.f/80.f);
        float lcnA  = (raw[c][ty + 4][tx + 4] - meanA) / (stdA + 1e-5f);
        float meanB = SB * (1.f/81.f);
        float stdB  = sqrtf(fmaxf(SB2 * (1.f/81.f) - meanB * meanB, 0.f)) * (81.f/80.f);
        float lcnB  = (raw[3 + c][ty + 4][tx + 4] - meanB) / (stdB + 1e-5f);
        float cost  = fabsf((lcnA - lcnB) * stdA);
        if (blockIdx.z == 0) {
            float g = raw[c][ty + 4][tx + 4];
            epem[c*HW + idx] = bf16rne(__expf(0.5f * g)) | (bf16rne(__expf(-0.5f * g)) << 16);
            cl16[c*HW + idx] = (unsigned short)bf16rne(cost);
        } else {
            cr16[c*HW + idx] = (unsigned short)bf16rne(cost);
        }
    }
}

// ---------------- K3: 12x12 ASW + reduction (channel-per-block) ----------------
// block (32,4) = 128 threads = 2 waves; channel c = blockIdx.z; thread (tx,ty):
// 4 outputs (gx0+tx, gy0+4ty+i), i=0..3; region 32x16/block; grid (20,30,3)=1800.
// Tile uint2: .x = bf16(Ep)|bf16(Em)<<16; .y = bf16(costL)|bf16(costR)<<16.
// OOB halo: g=0 => Ep=Em=1.0, costs 0 (matches zero-pad reference).
// Per tap: t = exp(-|g_c-g_q|/2) = min(Em_c*Ep_q, Ep_c*Em_q).

#define T3H 27
#define T3W 43

__global__ __launch_bounds__(128) void k_asw_reduce(
    const unsigned* __restrict__ epem,
    const unsigned short* __restrict__ cl16, const unsigned short* __restrict__ cr16,
    const unsigned char* __restrict__ maskb,
    float* __restrict__ part3)
{
    __shared__ uint2 tile[T3H][T3W];   // 9288 B
    __shared__ float red[2][2];
    int tx = threadIdx.x, ty = threadIdx.y;
    int tid = tx + 32 * ty;
    int c = blockIdx.z;
    int gx0 = blockIdx.x * 32, gy0 = blockIdx.y * 16;

    for (int e = tid; e < T3H * T3W; e += 128) {
        int r   = e / T3W;
        int x   = e - r * T3W;
        int gy = gy0 + r - 6, gx = gx0 + x - 6;
        uint2 v = make_uint2(0x3f803f80u, 0u);   // g=0: Ep=Em=1.0, costs 0
        if ((unsigned)gy < (unsigned)HH && (unsigned)gx < (unsigned)WW) {
            int o = c*HW + gy*WW + gx;
            v.x = epem[o];
            v.y = (unsigned)cl16[o] | ((unsigned)cr16[o] << 16);
        }
        tile[r][x] = v;
    }
    __syncthreads();

    int ty4 = 4 * ty;
    float epc[4], emc[4];
    #pragma unroll
    for (int i = 0; i < 4; ++i) {
        unsigned vc = tile[ty4 + i + 6][tx + 6].x;
        epc[i] = __uint_as_float(vc << 16);
        emc[i] = __uint_as_float(vc & 0xffff0000u);
    }

    float wg[4] = {0.f,0.f,0.f,0.f}, aL[4] = {0.f,0.f,0.f,0.f}, aR[4] = {0.f,0.f,0.f,0.f};

    auto taprow = [&](int kap, int i0, int i1) {
        int r = ty4 + kap;
        #pragma unroll
        for (int dx = 0; dx < 12; ++dx) {
            uint2 v = tile[r][tx + dx];
            float ep = __uint_as_float(v.x << 16);
            float em = __uint_as_float(v.x & 0xffff0000u);
            float clv = __uint_as_float(v.y << 16);
            float crv = __uint_as_float(v.y & 0xffff0000u);
            #pragma unroll
            for (int i = 0; i < 4; ++i) {
                if (i >= i0 && i <= i1) {
                    float t = fminf(emc[i] * ep, epc[i] * em);
                    wg[i] += t;
                    aL[i] = fmaf(t, clv, aL[i]);
                    aR[i] = fmaf(t, crv, aR[i]);
                }
            }
        }
    };

    taprow(0, 0, 0);
    taprow(1, 0, 1);
    taprow(2, 0, 2);
    for (int kap = 3; kap <= 11; ++kap)   // rolled bulk: all 4 outputs eligible
        taprow(kap, 0, 3);
    taprow(12, 1, 3);
    taprow(13, 2, 3);
    taprow(14, 3, 3);

    float v0 = 0.f, v2 = 0.f;
    #pragma unroll
    for (int i = 0; i < 4; ++i) {
        int idx = (gy0 + ty4 + i) * WW + gx0 + tx;
        unsigned m = maskb[idx];
        float aswL = aL[i] / wg[i];
        float aswR = aR[i] / wg[i];
        if (m & 1u) v0 += 0.5f * aswL;
        if (m & 2u) v2 += 0.5f * aswR;
    }

    int lane = tid & 63, wave = tid >> 6;
    {
        float a0 = v0, a2 = v2;
        #pragma unroll
        for (int off = 32; off > 0; off >>= 1) {
            a0 += __shfl_down(a0, off);
            a2 += __shfl_down(a2, off);
        }
        if (lane == 0) { red[wave][0] = a0; red[wave][1] = a2; }
    }
    __syncthreads();
    if (tid == 0) {
        int bid = (blockIdx.z * gridDim.y + blockIdx.y) * gridDim.x + blockIdx.x;
        part3[bid * 8 + 0] = red[0][0] + red[1][0];
        part3[bid * 8 + 1] = red[0][1] + red[1][1];
    }
}

// ---------------- K4: reduce partials + finalize ----------------

__global__ __launch_bounds__(256) void k_final(
    const float* __restrict__ part1, const float* __restrict__ part3,
    const float* __restrict__ weight, float* __restrict__ out)
{
    __shared__ float red[4][6];
    int tid = threadIdx.x;
    float v[6] = {0.f, 0.f, 0.f, 0.f, 0.f, 0.f};
    for (int b = tid; b < NB1; b += 256) {
        #pragma unroll
        for (int k = 0; k < 6; ++k) v[k] += part1[b * 8 + k];
    }
    for (int b = tid; b < NB3; b += 256) {
        v[0] += part3[b * 8 + 0];
        v[2] += part3[b * 8 + 1];
    }
    int lane = tid & 63, wave = tid >> 6;
    #pragma unroll
    for (int k = 0; k < 6; ++k) {
        float s = v[k];
        #pragma unroll
        for (int off = 32; off > 0; off >>= 1) s += __shfl_down(s, off);
        if (lane == 0) red[wave][k] = s;
    }
    __syncthreads();
    if (tid == 0) {
        float a[6];
        #pragma unroll
        for (int k = 0; k < 6; ++k)
            a[k] = red[0][k] + red[1][k] + red[2][k] + red[3][k];
        float loss_valid = a[0] / (3.f * a[1] + 1e-6f) + a[2] / (3.f * a[3] + 1e-6f);
        float loss_invalid = (a[4] + a[5]) * (1.f / (float)HW);
        out[0] = weight[0] * (0.9f * loss_valid + 0.1f * loss_invalid);
    }
}

// ---------------- launch ----------------

extern "C" void kernel_launch(void* const* d_in, const int* in_sizes, int n_in,
                              void* d_out, int out_size, void* d_ws, size_t ws_size,
                              hipStream_t stream)
{
    const float* left  = (const float*)d_in[0];
    const float* right = (const float*)d_in[1];
    const float* dispL = (const float*)d_in[2];
    const float* dispR = (const float*)d_in[3];
    // d_in[4] = dispmap_gt (unused), d_in[5] = brk (unused)
    const float* weight = (const float*)d_in[6];

    float* ws    = (float*)d_ws;
    float* rir   = ws;                                  // 3*HW f32
    float* ril   = rir + 3*HW;                          // 3*HW f32
    unsigned* epem = (unsigned*)(ws + 6*HW);            // 3*HW u32
    unsigned short* cl16 = (unsigned short*)(ws + 9*HW);            // 3*HW u16
    unsigned short* cr16 = (unsigned short*)(ws + 9*HW) + 3*HW;     // 3*HW u16
    unsigned char* maskb = (unsigned char*)(ws + 12*HW);            // HW bytes
    float* part1 = ws + 12*HW + HW/4;                   // NB1*8
    float* part3 = part1 + NB1*8;                       // NB3*8

    k_resample<<<NB1, 256, 0, stream>>>(left, right, dispL, dispR, rir, ril, maskb, part1);

    dim3 blk2(32, 8);
    dim3 grd2(WW / 32, HH / 8, 2);
    k_lcnpack<<<grd2, blk2, 0, stream>>>(left, right, rir, ril, epem, cl16, cr16);

    dim3 blk3(32, 4);
    dim3 grd3(WW / 32, HH / 16, 3);
    k_asw_reduce<<<grd3, blk3, 0, stream>>>(epem, cl16, cr16, maskb, part3);

    k_final<<<1, 256, 0, stream>>>(part1, part3, weight, (float*)d_out);
}

// Round 13
// 90.382 us; speedup vs baseline: 3.9085x; 1.0091x over previous
//
#include <hip/hip_runtime.h>
#include <math.h>

#define HH 480
#define WW 640
#define HW (HH*WW)

#define NB1 1200   // K1 blocks
#define NB3 1800   // K3 blocks (20 x 30 x 3)

__device__ __forceinline__ unsigned bf16rne(float f) {
    unsigned u = __float_as_uint(f);
    return (u + 0x7fffu + ((u >> 16) & 1u)) >> 16;
}

// ---------------- K1: resample + photo + CE + masks (partials, no atomics) ----------------

__device__ __forceinline__ float sample1(const float* __restrict__ row, float x) {
    float x0 = floorf(x);
    float w1 = x - x0;
    int xi = (int)x0;
    float v0 = (xi >= 0 && xi < WW) ? row[xi] : 0.f;
    float v1 = (xi + 1 >= 0 && xi + 1 < WW) ? row[xi + 1] : 0.f;
    return v0 * (1.f - w1) + v1 * w1;
}

__global__ __launch_bounds__(256) void k_resample(
    const float* __restrict__ left, const float* __restrict__ right,
    const float* __restrict__ dispL, const float* __restrict__ dispR,
    float* __restrict__ rir, float* __restrict__ ril,
    unsigned char* __restrict__ maskb, float* __restrict__ part1)
{
    __shared__ float red[4][6];
    int tid = threadIdx.x;
    int idx = blockIdx.x * blockDim.x + tid;
    int h = idx / WW;
    int w = idx - h * WW;
    float dL = dispL[idx];
    float dR = dispR[idx];
    float xl = (float)w - dL;   // sample right view at j - dispL
    float xr = (float)w + dR;   // sample left view  at j + dispR
    float photoL = 0.f, photoR = 0.f;
    #pragma unroll
    for (int c = 0; c < 3; ++c) {
        float rv = sample1(right + c*HW + h*WW, xl);
        float lv = sample1(left  + c*HW + h*WW, xr);
        rir[c*HW + idx] = rv;
        ril[c*HW + idx] = lv;
        photoL += fabsf(left [c*HW + idx] - rv);
        photoR += fabsf(right[c*HW + idx] - lv);
    }
    float rdr = sample1(dispR + h*WW, xl);
    float rdl = sample1(dispL + h*WW, xr);
    float pl = __expf(-0.6931f * fabsf(dL - rdr));
    float pr = __expf(-0.6931f * fabsf(dR - rdl));
    float mL = (pl > 0.5f) ? 1.f : 0.f;
    float mR = (pr > 0.5f) ? 1.f : 0.f;
    maskb[idx] = (unsigned char)((mL > 0.f ? 1u : 0u) | (mR > 0.f ? 2u : 0u));

    float vals[6];
    vals[0] = 0.5f * photoL * mL;
    vals[1] = mL;
    vals[2] = 0.5f * photoR * mR;
    vals[3] = mR;
    vals[4] = log1pf(__expf(1.f - 2.f * pl));
    vals[5] = log1pf(__expf(1.f - 2.f * pr));

    int lane = tid & 63, wave = tid >> 6;
    #pragma unroll
    for (int k = 0; k < 6; ++k) {
        float v = vals[k];
        #pragma unroll
        for (int off = 32; off > 0; off >>= 1) v += __shfl_down(v, off);
        if (lane == 0) red[wave][k] = v;
    }
    __syncthreads();
    if (tid < 6)
        part1[blockIdx.x * 8 + tid] =
            red[0][tid] + red[1][tid] + red[2][tid] + red[3][tid];
}

// ---------------- K2: 9x9 LCN (separable, vectorized LDS), one side per blockIdx.z ----------------
// block (32,8), region 32x8, halo 4: raw 16x40; grid (20,60,2) = 2400 blocks.
// hpass: per thread 3 groups of 4 consecutive outputs; 3 x ds_read_b128 + register
// sliding-window sums; store (s,s2) interleaved as float2 via 2 x b128.
// vpass: 9 x ds_read_b64 per (c, stream).
// z=0: A=left,  B=rir -> costL (bf16 cl16), Ep/Em(left) packed into epem.
// z=1: A=right, B=ril -> costR (bf16 cr16).

__global__ __launch_bounds__(256) void k_lcnpack(
    const float* __restrict__ left, const float* __restrict__ right,
    const float* __restrict__ rir, const float* __restrict__ ril,
    unsigned* __restrict__ epem,
    unsigned short* __restrict__ cl16, unsigned short* __restrict__ cr16)
{
    __shared__ float raw[6][16][40];    // 15360 B
    __shared__ float2 hsp[6][16][32];   // 24576 B  (.x = sum, .y = sumsq)
    int tx = threadIdx.x, ty = threadIdx.y;
    int tid = ty * 32 + tx;
    int gx0 = blockIdx.x * 32, gy0 = blockIdx.y * 8;
    const float* __restrict__ A = blockIdx.z ? right : left;   // real image (std source)
    const float* __restrict__ B = blockIdx.z ? ril   : rir;    // reconstruction

    for (int e = tid; e < 6*16*40; e += 256) {
        int a   = e / (16*40);
        int rem = e - a * (16*40);
        int r   = rem / 40;
        int x   = rem - r * 40;
        int gy = gy0 + r - 4, gx = gx0 + x - 4;
        float v = 0.f;
        if ((unsigned)gy < (unsigned)HH && (unsigned)gx < (unsigned)WW)
            v = (a < 3) ? A[a*HW + gy*WW + gx] : B[(a-3)*HW + gy*WW + gx];
        ((float*)raw)[e] = v;
    }
    __syncthreads();

    // hpass: 6*16*8 = 768 groups of 4 outputs = 3 per thread
    #pragma unroll
    for (int k = 0; k < 3; ++k) {
        int f   = tid + k * 256;
        int a   = f >> 7;          // /128
        int rem = f & 127;
        int r   = rem >> 3;
        int x0  = (rem & 7) * 4;
        const float* row = &raw[a][r][x0];
        float4 p0 = *(const float4*)(row);
        float4 p1 = *(const float4*)(row + 4);
        float4 p2 = *(const float4*)(row + 8);
        float v[12] = {p0.x, p0.y, p0.z, p0.w, p1.x, p1.y, p1.z, p1.w,
                       p2.x, p2.y, p2.z, p2.w};
        float sq[12];
        #pragma unroll
        for (int i = 0; i < 12; ++i) sq[i] = v[i] * v[i];
        float s0 = v[0]+v[1]+v[2]+v[3]+v[4]+v[5]+v[6]+v[7]+v[8];
        float q0 = sq[0]+sq[1]+sq[2]+sq[3]+sq[4]+sq[5]+sq[6]+sq[7]+sq[8];
        float s1 = s0 - v[0] + v[9];
        float q1 = q0 - sq[0] + sq[9];
        float s2 = s1 - v[1] + v[10];
        float q2 = q1 - sq[1] + sq[10];
        float s3 = s2 - v[2] + v[11];
        float q3 = q2 - sq[2] + sq[11];
        float4* out = (float4*)&hsp[a][r][x0];
        out[0] = make_float4(s0, q0, s1, q1);
        out[1] = make_float4(s2, q2, s3, q3);
    }
    __syncthreads();

    int idx = (gy0 + ty) * WW + gx0 + tx;
    #pragma unroll
    for (int c = 0; c < 3; ++c) {
        float SA = 0.f, SA2 = 0.f, SB = 0.f, SB2 = 0.f;
        #pragma unroll
        for (int dy = 0; dy < 9; ++dy) {
            float2 ha = hsp[c][ty + dy][tx];
            float2 hb = hsp[3 + c][ty + dy][tx];
            SA  += ha.x;
            SA2 += ha.y;
            SB  += hb.x;
            SB2 += hb.y;
        }
        float meanA = SA * (1.f/81.f);
        float stdA  = sqrtf(fmaxf(SA2 * (1.f/81.f) - meanA * meanA, 0.f)) * (81.f/80.f);
        float lcnA  = (raw[c][ty + 4][tx + 4] - meanA) / (stdA + 1e-5f);
        float meanB = SB * (1.f/81.f);
        float stdB  = sqrtf(fmaxf(SB2 * (1.f/81.f) - meanB * meanB, 0.f)) * (81.f/80.f);
        float lcnB  = (raw[3 + c][ty + 4][tx + 4] - meanB) / (stdB + 1e-5f);
        float cost  = fabsf((lcnA - lcnB) * stdA);
        if (blockIdx.z == 0) {
            float g = raw[c][ty + 4][tx + 4];
            epem[c*HW + idx] = bf16rne(__expf(0.5f * g)) | (bf16rne(__expf(-0.5f * g)) << 16);
            cl16[c*HW + idx] = (unsigned short)bf16rne(cost);
        } else {
            cr16[c*HW + idx] = (unsigned short)bf16rne(cost);
        }
    }
}

// ---------------- K3: 12x12 ASW + reduction (channel-per-block) ----------------
// block (32,4) = 128 threads = 2 waves; channel c = blockIdx.z; thread (tx,ty):
// 4 outputs (gx0+tx, gy0+4ty+i), i=0..3; region 32x16/block; grid (20,30,3)=1800.
// Tile uint2: .x = bf16(Ep)|bf16(Em)<<16; .y = bf16(costL)|bf16(costR)<<16.
// OOB halo: g=0 => Ep=Em=1.0, costs 0 (matches zero-pad reference).
// Per tap: t = exp(-|g_c-g_q|/2) = min(Em_c*Ep_q, Ep_c*Em_q).

#define T3H 27
#define T3W 43

__global__ __launch_bounds__(128) void k_asw_reduce(
    const unsigned* __restrict__ epem,
    const unsigned short* __restrict__ cl16, const unsigned short* __restrict__ cr16,
    const unsigned char* __restrict__ maskb,
    float* __restrict__ part3)
{
    __shared__ uint2 tile[T3H][T3W];   // 9288 B
    __shared__ float red[2][2];
    int tx = threadIdx.x, ty = threadIdx.y;
    int tid = tx + 32 * ty;
    int c = blockIdx.z;
    int gx0 = blockIdx.x * 32, gy0 = blockIdx.y * 16;

    for (int e = tid; e < T3H * T3W; e += 128) {
        int r   = e / T3W;
        int x   = e - r * T3W;
        int gy = gy0 + r - 6, gx = gx0 + x - 6;
        uint2 v = make_uint2(0x3f803f80u, 0u);   // g=0: Ep=Em=1.0, costs 0
        if ((unsigned)gy < (unsigned)HH && (unsigned)gx < (unsigned)WW) {
            int o = c*HW + gy*WW + gx;
            v.x = epem[o];
            v.y = (unsigned)cl16[o] | ((unsigned)cr16[o] << 16);
        }
        tile[r][x] = v;
    }
    __syncthreads();

    int ty4 = 4 * ty;
    float epc[4], emc[4];
    #pragma unroll
    for (int i = 0; i < 4; ++i) {
        unsigned vc = tile[ty4 + i + 6][tx + 6].x;
        epc[i] = __uint_as_float(vc << 16);
        emc[i] = __uint_as_float(vc & 0xffff0000u);
    }

    float wg[4] = {0.f,0.f,0.f,0.f}, aL[4] = {0.f,0.f,0.f,0.f}, aR[4] = {0.f,0.f,0.f,0.f};

    auto taprow = [&](int kap, int i0, int i1) {
        int r = ty4 + kap;
        #pragma unroll
        for (int dx = 0; dx < 12; ++dx) {
            uint2 v = tile[r][tx + dx];
            float ep = __uint_as_float(v.x << 16);
            float em = __uint_as_float(v.x & 0xffff0000u);
            float clv = __uint_as_float(v.y << 16);
            float crv = __uint_as_float(v.y & 0xffff0000u);
            #pragma unroll
            for (int i = 0; i < 4; ++i) {
                if (i >= i0 && i <= i1) {
                    float t = fminf(emc[i] * ep, epc[i] * em);
                    wg[i] += t;
                    aL[i] = fmaf(t, clv, aL[i]);
                    aR[i] = fmaf(t, crv, aR[i]);
                }
            }
        }
    };

    taprow(0, 0, 0);
    taprow(1, 0, 1);
    taprow(2, 0, 2);
    for (int kap = 3; kap <= 11; ++kap)   // rolled bulk: all 4 outputs eligible
        taprow(kap, 0, 3);
    taprow(12, 1, 3);
    taprow(13, 2, 3);
    taprow(14, 3, 3);

    float v0 = 0.f, v2 = 0.f;
    #pragma unroll
    for (int i = 0; i < 4; ++i) {
        int idx = (gy0 + ty4 + i) * WW + gx0 + tx;
        unsigned m = maskb[idx];
        float aswL = aL[i] / wg[i];
        float aswR = aR[i] / wg[i];
        if (m & 1u) v0 += 0.5f * aswL;
        if (m & 2u) v2 += 0.5f * aswR;
    }

    int lane = tid & 63, wave = tid >> 6;
    {
        float a0 = v0, a2 = v2;
        #pragma unroll
        for (int off = 32; off > 0; off >>= 1) {
            a0 += __shfl_down(a0, off);
            a2 += __shfl_down(a2, off);
        }
        if (lane == 0) { red[wave][0] = a0; red[wave][1] = a2; }
    }
    __syncthreads();
    if (tid == 0) {
        int bid = (blockIdx.z * gridDim.y + blockIdx.y) * gridDim.x + blockIdx.x;
        part3[bid * 8 + 0] = red[0][0] + red[1][0];
        part3[bid * 8 + 1] = red[0][1] + red[1][1];
    }
}

// ---------------- K4: reduce partials + finalize ----------------

__global__ __launch_bounds__(256) void k_final(
    const float* __restrict__ part1, const float* __restrict__ part3,
    const float* __restrict__ weight, float* __restrict__ out)
{
    __shared__ float red[4][6];
    int tid = threadIdx.x;
    float v[6] = {0.f, 0.f, 0.f, 0.f, 0.f, 0.f};
    for (int b = tid; b < NB1; b += 256) {
        #pragma unroll
        for (int k = 0; k < 6; ++k) v[k] += part1[b * 8 + k];
    }
    for (int b = tid; b < NB3; b += 256) {
        v[0] += part3[b * 8 + 0];
        v[2] += part3[b * 8 + 1];
    }
    int lane = tid & 63, wave = tid >> 6;
    #pragma unroll
    for (int k = 0; k < 6; ++k) {
        float s = v[k];
        #pragma unroll
        for (int off = 32; off > 0; off >>= 1) s += __shfl_down(s, off);
        if (lane == 0) red[wave][k] = s;
    }
    __syncthreads();
    if (tid == 0) {
        float a[6];
        #pragma unroll
        for (int k = 0; k < 6; ++k)
            a[k] = red[0][k] + red[1][k] + red[2][k] + red[3][k];
        float loss_valid = a[0] / (3.f * a[1] + 1e-6f) + a[2] / (3.f * a[3] + 1e-6f);
        float loss_invalid = (a[4] + a[5]) * (1.f / (float)HW);
        out[0] = weight[0] * (0.9f * loss_valid + 0.1f * loss_invalid);
    }
}

// ---------------- launch ----------------

extern "C" void kernel_launch(void* const* d_in, const int* in_sizes, int n_in,
                              void* d_out, int out_size, void* d_ws, size_t ws_size,
                              hipStream_t stream)
{
    const float* left  = (const float*)d_in[0];
    const float* right = (const float*)d_in[1];
    const float* dispL = (const float*)d_in[2];
    const float* dispR = (const float*)d_in[3];
    // d_in[4] = dispmap_gt (unused), d_in[5] = brk (unused)
    const float* weight = (const float*)d_in[6];

    float* ws    = (float*)d_ws;
    float* rir   = ws;                                  // 3*HW f32
    float* ril   = rir + 3*HW;                          // 3*HW f32
    unsigned* epem = (unsigned*)(ws + 6*HW);            // 3*HW u32
    unsigned short* cl16 = (unsigned short*)(ws + 9*HW);            // 3*HW u16
    unsigned short* cr16 = (unsigned short*)(ws + 9*HW) + 3*HW;     // 3*HW u16
    unsigned char* maskb = (unsigned char*)(ws + 12*HW);            // HW bytes
    float* part1 = ws + 12*HW + HW/4;                   // NB1*8
    float* part3 = part1 + NB1*8;                       // NB3*8

    k_resample<<<NB1, 256, 0, stream>>>(left, right, dispL, dispR, rir, ril, maskb, part1);

    dim3 blk2(32, 8);
    dim3 grd2(WW / 32, HH / 8, 2);
    k_lcnpack<<<grd2, blk2, 0, stream>>>(left, right, rir, ril, epem, cl16, cr16);

    dim3 blk3(32, 4);
    dim3 grd3(WW / 32, HH / 16, 3);
    k_asw_reduce<<<grd3, blk3, 0, stream>>>(epem, cl16, cr16, maskb, part3);

    k_final<<<1, 256, 0, stream>>>(part1, part3, weight, (float*)d_out);
}

// Round 14
// 87.614 us; speedup vs baseline: 4.0320x; 1.0316x over previous
//
#include <hip/hip_runtime.h>
#include <math.h>

#define HH 480
#define WW 640
#define HW (HH*WW)

#define NB1 1200   // K1 blocks
#define NB3 3600   // K3 blocks (20 x 60 x 3)

__device__ __forceinline__ unsigned bf16rne(float f) {
    unsigned u = __float_as_uint(f);
    return (u + 0x7fffu + ((u >> 16) & 1u)) >> 16;
}

// ---------------- K1: resample + photo + CE + masks (partials, no atomics) ----------------

__device__ __forceinline__ float sample1(const float* __restrict__ row, float x) {
    float x0 = floorf(x);
    float w1 = x - x0;
    int xi = (int)x0;
    float v0 = (xi >= 0 && xi < WW) ? row[xi] : 0.f;
    float v1 = (xi + 1 >= 0 && xi + 1 < WW) ? row[xi + 1] : 0.f;
    return v0 * (1.f - w1) + v1 * w1;
}

__global__ __launch_bounds__(256) void k_resample(
    const float* __restrict__ left, const float* __restrict__ right,
    const float* __restrict__ dispL, const float* __restrict__ dispR,
    float* __restrict__ rir, float* __restrict__ ril,
    unsigned char* __restrict__ maskb, float* __restrict__ part1)
{
    __shared__ float red[4][6];
    int tid = threadIdx.x;
    int idx = blockIdx.x * blockDim.x + tid;
    int h = idx / WW;
    int w = idx - h * WW;
    float dL = dispL[idx];
    float dR = dispR[idx];
    float xl = (float)w - dL;   // sample right view at j - dispL
    float xr = (float)w + dR;   // sample left view  at j + dispR
    float photoL = 0.f, photoR = 0.f;
    #pragma unroll
    for (int c = 0; c < 3; ++c) {
        float rv = sample1(right + c*HW + h*WW, xl);
        float lv = sample1(left  + c*HW + h*WW, xr);
        rir[c*HW + idx] = rv;
        ril[c*HW + idx] = lv;
        photoL += fabsf(left [c*HW + idx] - rv);
        photoR += fabsf(right[c*HW + idx] - lv);
    }
    float rdr = sample1(dispR + h*WW, xl);
    float rdl = sample1(dispL + h*WW, xr);
    float pl = __expf(-0.6931f * fabsf(dL - rdr));
    float pr = __expf(-0.6931f * fabsf(dR - rdl));
    float mL = (pl > 0.5f) ? 1.f : 0.f;
    float mR = (pr > 0.5f) ? 1.f : 0.f;
    maskb[idx] = (unsigned char)((mL > 0.f ? 1u : 0u) | (mR > 0.f ? 2u : 0u));

    float vals[6];
    vals[0] = 0.5f * photoL * mL;
    vals[1] = mL;
    vals[2] = 0.5f * photoR * mR;
    vals[3] = mR;
    vals[4] = log1pf(__expf(1.f - 2.f * pl));
    vals[5] = log1pf(__expf(1.f - 2.f * pr));

    int lane = tid & 63, wave = tid >> 6;
    #pragma unroll
    for (int k = 0; k < 6; ++k) {
        float v = vals[k];
        #pragma unroll
        for (int off = 32; off > 0; off >>= 1) v += __shfl_down(v, off);
        if (lane == 0) red[wave][k] = v;
    }
    __syncthreads();
    if (tid < 6)
        part1[blockIdx.x * 8 + tid] =
            red[0][tid] + red[1][tid] + red[2][tid] + red[3][tid];
}

// ---------------- K2: 9x9 LCN (separable, vectorized LDS), one side per blockIdx.z ----------------

__global__ __launch_bounds__(256) void k_lcnpack(
    const float* __restrict__ left, const float* __restrict__ right,
    const float* __restrict__ rir, const float* __restrict__ ril,
    unsigned* __restrict__ epem,
    unsigned short* __restrict__ cl16, unsigned short* __restrict__ cr16)
{
    __shared__ float raw[6][16][40];    // 15360 B
    __shared__ float2 hsp[6][16][32];   // 24576 B  (.x = sum, .y = sumsq)
    int tx = threadIdx.x, ty = threadIdx.y;
    int tid = ty * 32 + tx;
    int gx0 = blockIdx.x * 32, gy0 = blockIdx.y * 8;
    const float* __restrict__ A = blockIdx.z ? right : left;   // real image (std source)
    const float* __restrict__ B = blockIdx.z ? ril   : rir;    // reconstruction

    for (int e = tid; e < 6*16*40; e += 256) {
        int a   = e / (16*40);
        int rem = e - a * (16*40);
        int r   = rem / 40;
        int x   = rem - r * 40;
        int gy = gy0 + r - 4, gx = gx0 + x - 4;
        float v = 0.f;
        if ((unsigned)gy < (unsigned)HH && (unsigned)gx < (unsigned)WW)
            v = (a < 3) ? A[a*HW + gy*WW + gx] : B[(a-3)*HW + gy*WW + gx];
        ((float*)raw)[e] = v;
    }
    __syncthreads();

    // hpass: 6*16*8 = 768 groups of 4 outputs = 3 per thread
    #pragma unroll
    for (int k = 0; k < 3; ++k) {
        int f   = tid + k * 256;
        int a   = f >> 7;          // /128
        int rem = f & 127;
        int r   = rem >> 3;
        int x0  = (rem & 7) * 4;
        const float* row = &raw[a][r][x0];
        float4 p0 = *(const float4*)(row);
        float4 p1 = *(const float4*)(row + 4);
        float4 p2 = *(const float4*)(row + 8);
        float v[12] = {p0.x, p0.y, p0.z, p0.w, p1.x, p1.y, p1.z, p1.w,
                       p2.x, p2.y, p2.z, p2.w};
        float sq[12];
        #pragma unroll
        for (int i = 0; i < 12; ++i) sq[i] = v[i] * v[i];
        float s0 = v[0]+v[1]+v[2]+v[3]+v[4]+v[5]+v[6]+v[7]+v[8];
        float q0 = sq[0]+sq[1]+sq[2]+sq[3]+sq[4]+sq[5]+sq[6]+sq[7]+sq[8];
        float s1 = s0 - v[0] + v[9];
        float q1 = q0 - sq[0] + sq[9];
        float s2 = s1 - v[1] + v[10];
        float q2 = q1 - sq[1] + sq[10];
        float s3 = s2 - v[2] + v[11];
        float q3 = q2 - sq[2] + sq[11];
        float4* out = (float4*)&hsp[a][r][x0];
        out[0] = make_float4(s0, q0, s1, q1);
        out[1] = make_float4(s2, q2, s3, q3);
    }
    __syncthreads();

    int idx = (gy0 + ty) * WW + gx0 + tx;
    #pragma unroll
    for (int c = 0; c < 3; ++c) {
        float SA = 0.f, SA2 = 0.f, SB = 0.f, SB2 = 0.f;
        #pragma unroll
        for (int dy = 0; dy < 9; ++dy) {
            float2 ha = hsp[c][ty + dy][tx];
            float2 hb = hsp[3 + c][ty + dy][tx];
            SA  += ha.x;
            SA2 += ha.y;
            SB  += hb.x;
            SB2 += hb.y;
        }
        float meanA = SA * (1.f/81.f);
        float stdA  = sqrtf(fmaxf(SA2 * (1.f/81.f) - meanA * meanA, 0.f)) * (81.f/80.f);
        float lcnA  = (raw[c][ty + 4][tx + 4] - meanA) / (stdA + 1e-5f);
        float meanB = SB * (1.f/81.f);
        float stdB  = sqrtf(fmaxf(SB2 * (1.f/81.f) - meanB * meanB, 0.f)) * (81.f/80.f);
        float lcnB  = (raw[3 + c][ty + 4][tx + 4] - meanB) / (stdB + 1e-5f);
        float cost  = fabsf((lcnA - lcnB) * stdA);
        if (blockIdx.z == 0) {
            float g = raw[c][ty + 4][tx + 4];
            epem[c*HW + idx] = bf16rne(__expf(0.5f * g)) | (bf16rne(__expf(-0.5f * g)) << 16);
            cl16[c*HW + idx] = (unsigned short)bf16rne(cost);
        } else {
            cr16[c*HW + idx] = (unsigned short)bf16rne(cost);
        }
    }
}

// ---------------- K3: 12x12 ASW + reduction (1-wave blocks, unpacked f32 tile) ----------------
// block (32,2) = 64 threads = 1 wave; channel c = blockIdx.z; thread (tx,ty):
// 4 outputs (gx0+tx, gy0+4ty+i), i=0..3; region 32x8/block; grid (20,60,3)=3600.
// Tile float4 = (Ep, Em, cL, cR), all f32 (pre-expanded from bf16 at staging).
// OOB halo: g=0 => Ep=Em=1.0, costs 0 (matches zero-pad reference).
// Per tap: t = exp(-|g_c-g_q|/2) = min(Em_c*Ep_q, Ep_c*Em_q) — no unpack in the loop.

#define T3H 19
#define T3W 43

__global__ __launch_bounds__(64) void k_asw_reduce(
    const unsigned* __restrict__ epem,
    const unsigned short* __restrict__ cl16, const unsigned short* __restrict__ cr16,
    const unsigned char* __restrict__ maskb,
    float* __restrict__ part3)
{
    __shared__ float4 tile[T3H][T3W];   // 13072 B
    int tx = threadIdx.x, ty = threadIdx.y;
    int tid = tx + 32 * ty;
    int c = blockIdx.z;
    int gx0 = blockIdx.x * 32, gy0 = blockIdx.y * 8;

    for (int e = tid; e < T3H * T3W; e += 64) {
        int r   = e / T3W;
        int x   = e - r * T3W;
        int gy = gy0 + r - 6, gx = gx0 + x - 6;
        float4 v = make_float4(1.f, 1.f, 0.f, 0.f);   // g=0: Ep=Em=1, costs 0
        if ((unsigned)gy < (unsigned)HH && (unsigned)gx < (unsigned)WW) {
            int o = c*HW + gy*WW + gx;
            unsigned pe = epem[o];
            v.x = __uint_as_float(pe << 16);
            v.y = __uint_as_float(pe & 0xffff0000u);
            v.z = __uint_as_float((unsigned)cl16[o] << 16);
            v.w = __uint_as_float((unsigned)cr16[o] << 16);
        }
        tile[r][x] = v;
    }
    __syncthreads();

    int ty4 = 4 * ty;
    float epc[4], emc[4];
    #pragma unroll
    for (int i = 0; i < 4; ++i) {
        float4 cv = tile[ty4 + i + 6][tx + 6];
        epc[i] = cv.x;
        emc[i] = cv.y;
    }

    float wg[4] = {0.f,0.f,0.f,0.f}, aL[4] = {0.f,0.f,0.f,0.f}, aR[4] = {0.f,0.f,0.f,0.f};

    auto taprow = [&](int kap, int i0, int i1) {
        const float4* row = &tile[ty4 + kap][tx];
        #pragma unroll
        for (int dx = 0; dx < 12; ++dx) {
            float4 v = row[dx];
            #pragma unroll
            for (int i = 0; i < 4; ++i) {
                if (i >= i0 && i <= i1) {
                    float t = fminf(emc[i] * v.x, epc[i] * v.y);
                    wg[i] += t;
                    aL[i] = fmaf(t, v.z, aL[i]);
                    aR[i] = fmaf(t, v.w, aR[i]);
                }
            }
        }
    };

    taprow(0, 0, 0);
    taprow(1, 0, 1);
    taprow(2, 0, 2);
    for (int kap = 3; kap <= 11; ++kap)   // rolled bulk: all 4 outputs eligible
        taprow(kap, 0, 3);
    taprow(12, 1, 3);
    taprow(13, 2, 3);
    taprow(14, 3, 3);

    float v0 = 0.f, v2 = 0.f;
    #pragma unroll
    for (int i = 0; i < 4; ++i) {
        int idx = (gy0 + ty4 + i) * WW + gx0 + tx;
        unsigned m = maskb[idx];
        float aswL = aL[i] / wg[i];
        float aswR = aR[i] / wg[i];
        if (m & 1u) v0 += 0.5f * aswL;
        if (m & 2u) v2 += 0.5f * aswR;
    }

    #pragma unroll
    for (int off = 32; off > 0; off >>= 1) {
        v0 += __shfl_down(v0, off);
        v2 += __shfl_down(v2, off);
    }
    if (tid == 0) {
        int bid = (blockIdx.z * gridDim.y + blockIdx.y) * gridDim.x + blockIdx.x;
        part3[bid * 8 + 0] = v0;
        part3[bid * 8 + 1] = v2;
    }
}

// ---------------- K4: reduce partials + finalize ----------------

__global__ __launch_bounds__(256) void k_final(
    const float* __restrict__ part1, const float* __restrict__ part3,
    const float* __restrict__ weight, float* __restrict__ out)
{
    __shared__ float red[4][6];
    int tid = threadIdx.x;
    float v[6] = {0.f, 0.f, 0.f, 0.f, 0.f, 0.f};
    for (int b = tid; b < NB1; b += 256) {
        #pragma unroll
        for (int k = 0; k < 6; ++k) v[k] += part1[b * 8 + k];
    }
    for (int b = tid; b < NB3; b += 256) {
        v[0] += part3[b * 8 + 0];
        v[2] += part3[b * 8 + 1];
    }
    int lane = tid & 63, wave = tid >> 6;
    #pragma unroll
    for (int k = 0; k < 6; ++k) {
        float s = v[k];
        #pragma unroll
        for (int off = 32; off > 0; off >>= 1) s += __shfl_down(s, off);
        if (lane == 0) red[wave][k] = s;
    }
    __syncthreads();
    if (tid == 0) {
        float a[6];
        #pragma unroll
        for (int k = 0; k < 6; ++k)
            a[k] = red[0][k] + red[1][k] + red[2][k] + red[3][k];
        float loss_valid = a[0] / (3.f * a[1] + 1e-6f) + a[2] / (3.f * a[3] + 1e-6f);
        float loss_invalid = (a[4] + a[5]) * (1.f / (float)HW);
        out[0] = weight[0] * (0.9f * loss_valid + 0.1f * loss_invalid);
    }
}

// ---------------- launch ----------------

extern "C" void kernel_launch(void* const* d_in, const int* in_sizes, int n_in,
                              void* d_out, int out_size, void* d_ws, size_t ws_size,
                              hipStream_t stream)
{
    const float* left  = (const float*)d_in[0];
    const float* right = (const float*)d_in[1];
    const float* dispL = (const float*)d_in[2];
    const float* dispR = (const float*)d_in[3];
    // d_in[4] = dispmap_gt (unused), d_in[5] = brk (unused)
    const float* weight = (const float*)d_in[6];

    float* ws    = (float*)d_ws;
    float* rir   = ws;                                  // 3*HW f32
    float* ril   = rir + 3*HW;                          // 3*HW f32
    unsigned* epem = (unsigned*)(ws + 6*HW);            // 3*HW u32
    unsigned short* cl16 = (unsigned short*)(ws + 9*HW);            // 3*HW u16
    unsigned short* cr16 = (unsigned short*)(ws + 9*HW) + 3*HW;     // 3*HW u16
    unsigned char* maskb = (unsigned char*)(ws + 12*HW);            // HW bytes
    float* part1 = ws + 12*HW + HW/4;                   // NB1*8
    float* part3 = part1 + NB1*8;                       // NB3*8

    k_resample<<<NB1, 256, 0, stream>>>(left, right, dispL, dispR, rir, ril, maskb, part1);

    dim3 blk2(32, 8);
    dim3 grd2(WW / 32, HH / 8, 2);
    k_lcnpack<<<grd2, blk2, 0, stream>>>(left, right, rir, ril, epem, cl16, cr16);

    dim3 blk3(32, 2);
    dim3 grd3(WW / 32, HH / 8, 3);
    k_asw_reduce<<<grd3, blk3, 0, stream>>>(epem, cl16, cr16, maskb, part3);

    k_final<<<1, 256, 0, stream>>>(part1, part3, weight, (float*)d_out);
}

// Round 15
// 75.772 us; speedup vs baseline: 4.6621x; 1.1563x over previous
//
#include <hip/hip_runtime.h>
#include <math.h>

#define HH 480
#define WW 640
#define HW (HH*WW)

#define NB1 1200   // K1 blocks
#define NB3 3600   // K3 blocks (20 x 60 x 3)

__device__ __forceinline__ unsigned bf16rne(float f) {
    unsigned u = __float_as_uint(f);
    return (u + 0x7fffu + ((u >> 16) & 1u)) >> 16;
}

// ---------------- K1: resample + photo + CE + masks (partials, no atomics) ----------------

__device__ __forceinline__ float sample1(const float* __restrict__ row, float x) {
    float x0 = floorf(x);
    float w1 = x - x0;
    int xi = (int)x0;
    float v0 = (xi >= 0 && xi < WW) ? row[xi] : 0.f;
    float v1 = (xi + 1 >= 0 && xi + 1 < WW) ? row[xi + 1] : 0.f;
    return v0 * (1.f - w1) + v1 * w1;
}

__global__ __launch_bounds__(256) void k_resample(
    const float* __restrict__ left, const float* __restrict__ right,
    const float* __restrict__ dispL, const float* __restrict__ dispR,
    float* __restrict__ rir, float* __restrict__ ril,
    unsigned char* __restrict__ maskb, float* __restrict__ part1)
{
    __shared__ float red[4][6];
    int tid = threadIdx.x;
    int idx = blockIdx.x * blockDim.x + tid;
    int h = idx / WW;
    int w = idx - h * WW;
    float dL = dispL[idx];
    float dR = dispR[idx];
    float xl = (float)w - dL;   // sample right view at j - dispL
    float xr = (float)w + dR;   // sample left view  at j + dispR
    float photoL = 0.f, photoR = 0.f;
    #pragma unroll
    for (int c = 0; c < 3; ++c) {
        float rv = sample1(right + c*HW + h*WW, xl);
        float lv = sample1(left  + c*HW + h*WW, xr);
        rir[c*HW + idx] = rv;
        ril[c*HW + idx] = lv;
        photoL += fabsf(left [c*HW + idx] - rv);
        photoR += fabsf(right[c*HW + idx] - lv);
    }
    float rdr = sample1(dispR + h*WW, xl);
    float rdl = sample1(dispL + h*WW, xr);
    float pl = __expf(-0.6931f * fabsf(dL - rdr));
    float pr = __expf(-0.6931f * fabsf(dR - rdl));
    float mL = (pl > 0.5f) ? 1.f : 0.f;
    float mR = (pr > 0.5f) ? 1.f : 0.f;
    maskb[idx] = (unsigned char)((mL > 0.f ? 1u : 0u) | (mR > 0.f ? 2u : 0u));

    float vals[6];
    vals[0] = 0.5f * photoL * mL;
    vals[1] = mL;
    vals[2] = 0.5f * photoR * mR;
    vals[3] = mR;
    vals[4] = log1pf(__expf(1.f - 2.f * pl));
    vals[5] = log1pf(__expf(1.f - 2.f * pr));

    int lane = tid & 63, wave = tid >> 6;
    #pragma unroll
    for (int k = 0; k < 6; ++k) {
        float v = vals[k];
        #pragma unroll
        for (int off = 32; off > 0; off >>= 1) v += __shfl_down(v, off);
        if (lane == 0) red[wave][k] = v;
    }
    __syncthreads();
    if (tid < 6)
        part1[blockIdx.x * 8 + tid] =
            red[0][tid] + red[1][tid] + red[2][tid] + red[3][tid];
}

// ---------------- K2: 9x9 LCN (separable), one (side,channel) per blockIdx.z ----------------
// block (32,8), region 32x8, halo 4: raw 16x40 per plane; grid (20,60,6) = 7200 blocks.
// z: side = z & 1, ch = z >> 1. side 0: A=left[ch], B=rir[ch] -> epem, cl16.
//                               side 1: A=right[ch], B=ril[ch] -> cr16.
// hpass: 1 group of 4 outputs per thread via 3 x ds_read_b128 + sliding-window sums.

__global__ __launch_bounds__(256) void k_lcnpack(
    const float* __restrict__ left, const float* __restrict__ right,
    const float* __restrict__ rir, const float* __restrict__ ril,
    unsigned* __restrict__ epem,
    unsigned short* __restrict__ cl16, unsigned short* __restrict__ cr16)
{
    __shared__ float raw[2][16][40];    // 5120 B
    __shared__ float2 hsp[2][16][32];   // 8192 B  (.x = sum, .y = sumsq)
    int tx = threadIdx.x, ty = threadIdx.y;
    int tid = ty * 32 + tx;
    int gx0 = blockIdx.x * 32, gy0 = blockIdx.y * 8;
    int side = blockIdx.z & 1, ch = blockIdx.z >> 1;
    const float* __restrict__ A = (side ? right : left) + ch*HW;   // real (std source)
    const float* __restrict__ B = (side ? ril   : rir) + ch*HW;    // reconstruction

    // stage: 2 planes x 16 x 40 = 1280 elems, 5 per thread
    for (int e = tid; e < 2*16*40; e += 256) {
        int a   = e >> 9;              // /640
        int rem = e & 511;
        int r   = rem / 40;
        int x   = rem - r * 40;
        int gy = gy0 + r - 4, gx = gx0 + x - 4;
        float v = 0.f;
        if ((unsigned)gy < (unsigned)HH && (unsigned)gx < (unsigned)WW)
            v = (a ? B : A)[gy*WW + gx];
        ((float*)raw)[e] = v;
    }
    __syncthreads();

    // hpass: 2*16*8 = 256 groups of 4 outputs = 1 per thread
    {
        int f   = tid;
        int a   = f >> 7;
        int rem = f & 127;
        int r   = rem >> 3;
        int x0  = (rem & 7) * 4;
        const float* row = &raw[a][r][x0];
        float4 p0 = *(const float4*)(row);
        float4 p1 = *(const float4*)(row + 4);
        float4 p2 = *(const float4*)(row + 8);
        float v[12] = {p0.x, p0.y, p0.z, p0.w, p1.x, p1.y, p1.z, p1.w,
                       p2.x, p2.y, p2.z, p2.w};
        float sq[12];
        #pragma unroll
        for (int i = 0; i < 12; ++i) sq[i] = v[i] * v[i];
        float s0 = v[0]+v[1]+v[2]+v[3]+v[4]+v[5]+v[6]+v[7]+v[8];
        float q0 = sq[0]+sq[1]+sq[2]+sq[3]+sq[4]+sq[5]+sq[6]+sq[7]+sq[8];
        float s1 = s0 - v[0] + v[9];
        float q1 = q0 - sq[0] + sq[9];
        float s2 = s1 - v[1] + v[10];
        float q2 = q1 - sq[1] + sq[10];
        float s3 = s2 - v[2] + v[11];
        float q3 = q2 - sq[2] + sq[11];
        float4* out = (float4*)&hsp[a][r][x0];
        out[0] = make_float4(s0, q0, s1, q1);
        out[1] = make_float4(s2, q2, s3, q3);
    }
    __syncthreads();

    int idx = ch*HW + (gy0 + ty) * WW + gx0 + tx;
    float SA = 0.f, SA2 = 0.f, SB = 0.f, SB2 = 0.f;
    #pragma unroll
    for (int dy = 0; dy < 9; ++dy) {
        float2 ha = hsp[0][ty + dy][tx];
        float2 hb = hsp[1][ty + dy][tx];
        SA  += ha.x;
        SA2 += ha.y;
        SB  += hb.x;
        SB2 += hb.y;
    }
    float meanA = SA * (1.f/81.f);
    float stdA  = sqrtf(fmaxf(SA2 * (1.f/81.f) - meanA * meanA, 0.f)) * (81.f/80.f);
    float lcnA  = (raw[0][ty + 4][tx + 4] - meanA) / (stdA + 1e-5f);
    float meanB = SB * (1.f/81.f);
    float stdB  = sqrtf(fmaxf(SB2 * (1.f/81.f) - meanB * meanB, 0.f)) * (81.f/80.f);
    float lcnB  = (raw[1][ty + 4][tx + 4] - meanB) / (stdB + 1e-5f);
    float cost  = fabsf((lcnA - lcnB) * stdA);
    if (side == 0) {
        float g = raw[0][ty + 4][tx + 4];
        epem[idx] = bf16rne(__expf(0.5f * g)) | (bf16rne(__expf(-0.5f * g)) << 16);
        cl16[idx] = (unsigned short)bf16rne(cost);
    } else {
        cr16[idx] = (unsigned short)bf16rne(cost);
    }
}

// ---------------- K3: 12x12 ASW + reduction (1-wave blocks, unpacked f32 tile) ----------------
// block (32,2) = 64 threads = 1 wave; channel c = blockIdx.z; thread (tx,ty):
// 4 outputs (gx0+tx, gy0+4ty+i), i=0..3; region 32x8/block; grid (20,60,3)=3600.
// Tile float4 = (Ep, Em, cL, cR), all f32 (pre-expanded from bf16 at staging).
// OOB halo: g=0 => Ep=Em=1.0, costs 0 (matches zero-pad reference).
// Per tap: t = exp(-|g_c-g_q|/2) = min(Em_c*Ep_q, Ep_c*Em_q) — no unpack in the loop.

#define T3H 19
#define T3W 43

__global__ __launch_bounds__(64) void k_asw_reduce(
    const unsigned* __restrict__ epem,
    const unsigned short* __restrict__ cl16, const unsigned short* __restrict__ cr16,
    const unsigned char* __restrict__ maskb,
    float* __restrict__ part3)
{
    __shared__ float4 tile[T3H][T3W];   // 13072 B
    int tx = threadIdx.x, ty = threadIdx.y;
    int tid = tx + 32 * ty;
    int c = blockIdx.z;
    int gx0 = blockIdx.x * 32, gy0 = blockIdx.y * 8;

    for (int e = tid; e < T3H * T3W; e += 64) {
        int r   = e / T3W;
        int x   = e - r * T3W;
        int gy = gy0 + r - 6, gx = gx0 + x - 6;
        float4 v = make_float4(1.f, 1.f, 0.f, 0.f);   // g=0: Ep=Em=1, costs 0
        if ((unsigned)gy < (unsigned)HH && (unsigned)gx < (unsigned)WW) {
            int o = c*HW + gy*WW + gx;
            unsigned pe = epem[o];
            v.x = __uint_as_float(pe << 16);
            v.y = __uint_as_float(pe & 0xffff0000u);
            v.z = __uint_as_float((unsigned)cl16[o] << 16);
            v.w = __uint_as_float((unsigned)cr16[o] << 16);
        }
        tile[r][x] = v;
    }
    __syncthreads();

    int ty4 = 4 * ty;
    float epc[4], emc[4];
    #pragma unroll
    for (int i = 0; i < 4; ++i) {
        float4 cv = tile[ty4 + i + 6][tx + 6];
        epc[i] = cv.x;
        emc[i] = cv.y;
    }

    float wg[4] = {0.f,0.f,0.f,0.f}, aL[4] = {0.f,0.f,0.f,0.f}, aR[4] = {0.f,0.f,0.f,0.f};

    auto taprow = [&](int kap, int i0, int i1) {
        const float4* row = &tile[ty4 + kap][tx];
        #pragma unroll
        for (int dx = 0; dx < 12; ++dx) {
            float4 v = row[dx];
            #pragma unroll
            for (int i = 0; i < 4; ++i) {
                if (i >= i0 && i <= i1) {
                    float t = fminf(emc[i] * v.x, epc[i] * v.y);
                    wg[i] += t;
                    aL[i] = fmaf(t, v.z, aL[i]);
                    aR[i] = fmaf(t, v.w, aR[i]);
                }
            }
        }
    };

    taprow(0, 0, 0);
    taprow(1, 0, 1);
    taprow(2, 0, 2);
    for (int kap = 3; kap <= 11; ++kap)   // rolled bulk: all 4 outputs eligible
        taprow(kap, 0, 3);
    taprow(12, 1, 3);
    taprow(13, 2, 3);
    taprow(14, 3, 3);

    float v0 = 0.f, v2 = 0.f;
    #pragma unroll
    for (int i = 0; i < 4; ++i) {
        int idx = (gy0 + ty4 + i) * WW + gx0 + tx;
        unsigned m = maskb[idx];
        float aswL = aL[i] / wg[i];
        float aswR = aR[i] / wg[i];
        if (m & 1u) v0 += 0.5f * aswL;
        if (m & 2u) v2 += 0.5f * aswR;
    }

    #pragma unroll
    for (int off = 32; off > 0; off >>= 1) {
        v0 += __shfl_down(v0, off);
        v2 += __shfl_down(v2, off);
    }
    if (tid == 0) {
        int bid = (blockIdx.z * gridDim.y + blockIdx.y) * gridDim.x + blockIdx.x;
        part3[bid * 8 + 0] = v0;
        part3[bid * 8 + 1] = v2;
    }
}

// ---------------- K4: reduce partials + finalize ----------------

__global__ __launch_bounds__(256) void k_final(
    const float* __restrict__ part1, const float* __restrict__ part3,
    const float* __restrict__ weight, float* __restrict__ out)
{
    __shared__ float red[4][6];
    int tid = threadIdx.x;
    float v[6] = {0.f, 0.f, 0.f, 0.f, 0.f, 0.f};
    for (int b = tid; b < NB1; b += 256) {
        #pragma unroll
        for (int k = 0; k < 6; ++k) v[k] += part1[b * 8 + k];
    }
    for (int b = tid; b < NB3; b += 256) {
        v[0] += part3[b * 8 + 0];
        v[2] += part3[b * 8 + 1];
    }
    int lane = tid & 63, wave = tid >> 6;
    #pragma unroll
    for (int k = 0; k < 6; ++k) {
        float s = v[k];
        #pragma unroll
        for (int off = 32; off > 0; off >>= 1) s += __shfl_down(s, off);
        if (lane == 0) red[wave][k] = s;
    }
    __syncthreads();
    if (tid == 0) {
        float a[6];
        #pragma unroll
        for (int k = 0; k < 6; ++k)
            a[k] = red[0][k] + red[1][k] + red[2][k] + red[3][k];
        float loss_valid = a[0] / (3.f * a[1] + 1e-6f) + a[2] / (3.f * a[3] + 1e-6f);
        float loss_invalid = (a[4] + a[5]) * (1.f / (float)HW);
        out[0] = weight[0] * (0.9f * loss_valid + 0.1f * loss_invalid);
    }
}

// ---------------- launch ----------------

extern "C" void kernel_launch(void* const* d_in, const int* in_sizes, int n_in,
                              void* d_out, int out_size, void* d_ws, size_t ws_size,
                              hipStream_t stream)
{
    const float* left  = (const float*)d_in[0];
    const float* right = (const float*)d_in[1];
    const float* dispL = (const float*)d_in[2];
    const float* dispR = (const float*)d_in[3];
    // d_in[4] = dispmap_gt (unused), d_in[5] = brk (unused)
    const float* weight = (const float*)d_in[6];

    float* ws    = (float*)d_ws;
    float* rir   = ws;                                  // 3*HW f32
    float* ril   = rir + 3*HW;                          // 3*HW f32
    unsigned* epem = (unsigned*)(ws + 6*HW);            // 3*HW u32
    unsigned short* cl16 = (unsigned short*)(ws + 9*HW);            // 3*HW u16
    unsigned short* cr16 = (unsigned short*)(ws + 9*HW) + 3*HW;     // 3*HW u16
    unsigned char* maskb = (unsigned char*)(ws + 12*HW);            // HW bytes
    float* part1 = ws + 12*HW + HW/4;                   // NB1*8
    float* part3 = part1 + NB1*8;                       // NB3*8

    k_resample<<<NB1, 256, 0, stream>>>(left, right, dispL, dispR, rir, ril, maskb, part1);

    dim3 blk2(32, 8);
    dim3 grd2(WW / 32, HH / 8, 6);
    k_lcnpack<<<grd2, blk2, 0, stream>>>(left, right, rir, ril, epem, cl16, cr16);

    dim3 blk3(32, 2);
    dim3 grd3(WW / 32, HH / 8, 3);
    k_asw_reduce<<<grd3, blk3, 0, stream>>>(epem, cl16, cr16, maskb, part3);

    k_final<<<1, 256, 0, stream>>>(part1, part3, weight, (float*)d_out);
}